// Round 2
// baseline (2716.332 us; speedup 1.0000x reference)
//
#include <hip/hip_runtime.h>
#include <math.h>

#define B_ROWS 131072
#define NE 2048
#define ZDIM 64
#define THREADS 256
#define NSLICE 4
#define SLICE (NE / NSLICE)  // 512

// ---------------------------------------------------------------------------
// Kernel 0: precompute 0.5*|e_j|^2 for each codebook row.
// ---------------------------------------------------------------------------
__global__ void enorm_kernel(const float* __restrict__ E,
                             float* __restrict__ eNormHalf) {
    int j = blockIdx.x * blockDim.x + threadIdx.x;
    if (j < NE) {
        float s = 0.f;
#pragma unroll
        for (int d = 0; d < ZDIM; ++d) {
            float v = E[j * ZDIM + d];
            s = fmaf(v, v, s);
        }
        eNormHalf[j] = 0.5f * s;
    }
}

// ---------------------------------------------------------------------------
// Shared device helper: encoder (x -> z[64]).
// ---------------------------------------------------------------------------
__device__ __forceinline__ void encode_row(
    const float* __restrict__ xin,
    const float* __restrict__ W1, const float* __restrict__ b1,
    const float* __restrict__ W2, const float* __restrict__ b2,
    const float* __restrict__ W3, const float* __restrict__ b3,
    const float* __restrict__ W4, const float* __restrict__ b4,
    float* __restrict__ z) {
    float h1[16];
#pragma unroll
    for (int k = 0; k < 16; ++k) {
        float a = b1[k];
#pragma unroll
        for (int i = 0; i < 5; ++i) a = fmaf(xin[i], W1[i * 16 + k], a);
        h1[k] = fmaxf(a, 0.f);
    }
    float h2[32];
#pragma unroll
    for (int k = 0; k < 32; ++k) {
        float a = b2[k];
#pragma unroll
        for (int i = 0; i < 16; ++i) a = fmaf(h1[i], W2[i * 32 + k], a);
        h2[k] = fmaxf(a, 0.f);
    }
    float h3[16];
#pragma unroll
    for (int k = 0; k < 16; ++k) {
        float a = b3[k];
#pragma unroll
        for (int i = 0; i < 32; ++i) a = fmaf(h2[i], W3[i * 16 + k], a);
        h3[k] = fmaxf(a, 0.f);
    }
#pragma unroll
    for (int k = 0; k < ZDIM; ++k) {
        float a = b4[k];
#pragma unroll
        for (int i = 0; i < 16; ++i) a = fmaf(h3[i], W4[i * 64 + k], a);
        z[k] = a;
    }
}

// ---------------------------------------------------------------------------
// Kernel A: per (row, codebook-slice) partial argmax of
// score_j = z.e_j - 0.5|e_j|^2  (argmax score == argmin d2).
// grid = (B/256, NSLICE). j is wave-uniform -> scalar loads of E overlap the
// fp32 FMA stream. 2048 blocks -> 8192 waves -> full occupancy at VGPR<=64.
// ---------------------------------------------------------------------------
__global__ __launch_bounds__(THREADS, 8) void scan_kernel(
    const float* __restrict__ x,
    const float* __restrict__ W1, const float* __restrict__ b1,
    const float* __restrict__ W2, const float* __restrict__ b2,
    const float* __restrict__ W3, const float* __restrict__ b3,
    const float* __restrict__ W4, const float* __restrict__ b4,
    const float* __restrict__ E, const float* __restrict__ eNormHalf,
    float* __restrict__ score_out /* [NSLICE][B] */,
    int* __restrict__ idx_out /* [NSLICE][B] */) {

    const int row = blockIdx.x * THREADS + threadIdx.x;
    const int slice = blockIdx.y;

    float xin[5];
#pragma unroll
    for (int i = 0; i < 5; ++i) xin[i] = x[row * 5 + i];

    float z[ZDIM];
    encode_row(xin, W1, b1, W2, b2, W3, b3, W4, b4, z);

    float best = -INFINITY;
    int bidx = slice * SLICE;
    const float4* __restrict__ E4 = reinterpret_cast<const float4*>(E);
    const int j0 = slice * SLICE;
#pragma unroll 2
    for (int j = j0; j < j0 + SLICE; ++j) {
        float a0 = 0.f, a1 = 0.f, a2 = 0.f, a3 = 0.f;
#pragma unroll
        for (int q = 0; q < ZDIM / 4; ++q) {
            float4 e = E4[j * (ZDIM / 4) + q];
            a0 = fmaf(z[4 * q + 0], e.x, a0);
            a1 = fmaf(z[4 * q + 1], e.y, a1);
            a2 = fmaf(z[4 * q + 2], e.z, a2);
            a3 = fmaf(z[4 * q + 3], e.w, a3);
        }
        float score = ((a0 + a1) + (a2 + a3)) - eNormHalf[j];
        // strict '>' keeps FIRST max -> matches jnp.argmin tie-break
        if (score > best) {
            best = score;
            bidx = j;
        }
    }
    score_out[slice * B_ROWS + row] = best;
    idx_out[slice * B_ROWS + row] = bidx;
}

// ---------------------------------------------------------------------------
// Kernel B: merge slice candidates (slice-ascending, strict '>' => exact same
// winner as monolithic loop), gather z_q, recompute encoder z, decoder,
// losses, per-block partial sums.
// ---------------------------------------------------------------------------
__global__ __launch_bounds__(THREADS) void finish_rows_kernel(
    const float* __restrict__ x,
    const float* __restrict__ W1, const float* __restrict__ b1,
    const float* __restrict__ W2, const float* __restrict__ b2,
    const float* __restrict__ W3, const float* __restrict__ b3,
    const float* __restrict__ W4, const float* __restrict__ b4,
    const float* __restrict__ W5, const float* __restrict__ b5,
    const float* __restrict__ W6, const float* __restrict__ b6,
    const float* __restrict__ W7, const float* __restrict__ b7,
    const float* __restrict__ W8, const float* __restrict__ b8,
    const float* __restrict__ E,
    const float* __restrict__ score_in, const int* __restrict__ idx_in,
    float* __restrict__ partials /* [gridDim.x * 2] */) {

    const int row = blockIdx.x * THREADS + threadIdx.x;

    // ---- merge candidates ----
    float best = -INFINITY;
    int bidx = 0;
#pragma unroll
    for (int s = 0; s < NSLICE; ++s) {
        float sc = score_in[s * B_ROWS + row];
        int ix = idx_in[s * B_ROWS + row];
        if (sc > best) {
            best = sc;
            bidx = ix;
        }
    }

    // ---- recompute z, gather zq ----
    float xin[5];
#pragma unroll
    for (int i = 0; i < 5; ++i) xin[i] = x[row * 5 + i];
    float z[ZDIM];
    encode_row(xin, W1, b1, W2, b2, W3, b3, W4, b4, z);

    float zq[ZDIM];
#pragma unroll
    for (int d = 0; d < ZDIM; ++d) zq[d] = E[bidx * ZDIM + d];

    float emb = 0.f;
#pragma unroll
    for (int d = 0; d < ZDIM; ++d) {
        float diff = z[d] - zq[d];
        emb = fmaf(diff, diff, emb);
    }
    emb *= 2.0f;  // embed_loss + BETA*commit_loss, BETA = 1

    // ---- decoder ----
    float g1[16];
#pragma unroll
    for (int k = 0; k < 16; ++k) {
        float a = b5[k];
#pragma unroll
        for (int i = 0; i < ZDIM; ++i) a = fmaf(zq[i], W5[i * 16 + k], a);
        g1[k] = fmaxf(a, 0.f);
    }
    float g2[32];
#pragma unroll
    for (int k = 0; k < 32; ++k) {
        float a = b6[k];
#pragma unroll
        for (int i = 0; i < 16; ++i) a = fmaf(g1[i], W6[i * 32 + k], a);
        g2[k] = fmaxf(a, 0.f);
    }
    float g3[16];
#pragma unroll
    for (int k = 0; k < 16; ++k) {
        float a = b7[k];
#pragma unroll
        for (int i = 0; i < 32; ++i) a = fmaf(g2[i], W7[i * 16 + k], a);
        g3[k] = fmaxf(a, 0.f);
    }
    float l2 = 0.f;
#pragma unroll
    for (int k = 0; k < 5; ++k) {
        float a = b8[k];
#pragma unroll
        for (int i = 0; i < 16; ++i) a = fmaf(g3[i], W8[i * 5 + k], a);
        float diff = xin[k] - a;
        l2 = fmaf(diff, diff, l2);
    }

    // ---- block reduction ----
#pragma unroll
    for (int off = 32; off > 0; off >>= 1) {
        l2 += __shfl_down(l2, off);
        emb += __shfl_down(emb, off);
    }
    __shared__ float sl[THREADS / 64], se[THREADS / 64];
    const int wid = threadIdx.x >> 6;
    if ((threadIdx.x & 63) == 0) {
        sl[wid] = l2;
        se[wid] = emb;
    }
    __syncthreads();
    if (threadIdx.x == 0) {
        float L = 0.f, Em = 0.f;
#pragma unroll
        for (int w = 0; w < THREADS / 64; ++w) {
            L += sl[w];
            Em += se[w];
        }
        partials[2 * blockIdx.x + 0] = L;
        partials[2 * blockIdx.x + 1] = Em;
    }
}

// ---------------------------------------------------------------------------
// Fallback monolithic kernel (used only if ws_size is too small).
// ---------------------------------------------------------------------------
__global__ __launch_bounds__(THREADS) void vqvae_main_kernel(
    const float* __restrict__ x,
    const float* __restrict__ W1, const float* __restrict__ b1,
    const float* __restrict__ W2, const float* __restrict__ b2,
    const float* __restrict__ W3, const float* __restrict__ b3,
    const float* __restrict__ W4, const float* __restrict__ b4,
    const float* __restrict__ W5, const float* __restrict__ b5,
    const float* __restrict__ W6, const float* __restrict__ b6,
    const float* __restrict__ W7, const float* __restrict__ b7,
    const float* __restrict__ W8, const float* __restrict__ b8,
    const float* __restrict__ E, const float* __restrict__ eNormHalf,
    float* __restrict__ partials) {

    const int row = blockIdx.x * blockDim.x + threadIdx.x;
    float l2 = 0.f, emb = 0.f;

    if (row < B_ROWS) {
        float xin[5];
#pragma unroll
        for (int i = 0; i < 5; ++i) xin[i] = x[row * 5 + i];
        float z[ZDIM];
        encode_row(xin, W1, b1, W2, b2, W3, b3, W4, b4, z);

        float best = -INFINITY;
        int bidx = 0;
        const float4* __restrict__ E4 = reinterpret_cast<const float4*>(E);
        for (int j = 0; j < NE; ++j) {
            float a0 = 0.f, a1 = 0.f, a2 = 0.f, a3 = 0.f;
#pragma unroll
            for (int q = 0; q < ZDIM / 4; ++q) {
                float4 e = E4[j * (ZDIM / 4) + q];
                a0 = fmaf(z[4 * q + 0], e.x, a0);
                a1 = fmaf(z[4 * q + 1], e.y, a1);
                a2 = fmaf(z[4 * q + 2], e.z, a2);
                a3 = fmaf(z[4 * q + 3], e.w, a3);
            }
            float score = ((a0 + a1) + (a2 + a3)) - eNormHalf[j];
            if (score > best) { best = score; bidx = j; }
        }
        float zq[ZDIM];
#pragma unroll
        for (int d = 0; d < ZDIM; ++d) zq[d] = E[bidx * ZDIM + d];
#pragma unroll
        for (int d = 0; d < ZDIM; ++d) {
            float diff = z[d] - zq[d];
            emb = fmaf(diff, diff, emb);
        }
        emb *= 2.0f;
        float g1[16];
#pragma unroll
        for (int k = 0; k < 16; ++k) {
            float a = b5[k];
#pragma unroll
            for (int i = 0; i < ZDIM; ++i) a = fmaf(zq[i], W5[i * 16 + k], a);
            g1[k] = fmaxf(a, 0.f);
        }
        float g2[32];
#pragma unroll
        for (int k = 0; k < 32; ++k) {
            float a = b6[k];
#pragma unroll
            for (int i = 0; i < 16; ++i) a = fmaf(g1[i], W6[i * 32 + k], a);
            g2[k] = fmaxf(a, 0.f);
        }
        float g3[16];
#pragma unroll
        for (int k = 0; k < 16; ++k) {
            float a = b7[k];
#pragma unroll
            for (int i = 0; i < 32; ++i) a = fmaf(g2[i], W7[i * 16 + k], a);
            g3[k] = fmaxf(a, 0.f);
        }
#pragma unroll
        for (int k = 0; k < 5; ++k) {
            float a = b8[k];
#pragma unroll
            for (int i = 0; i < 16; ++i) a = fmaf(g3[i], W8[i * 5 + k], a);
            float diff = xin[k] - a;
            l2 = fmaf(diff, diff, l2);
        }
    }
#pragma unroll
    for (int off = 32; off > 0; off >>= 1) {
        l2 += __shfl_down(l2, off);
        emb += __shfl_down(emb, off);
    }
    __shared__ float sl[THREADS / 64], se[THREADS / 64];
    const int wid = threadIdx.x >> 6;
    if ((threadIdx.x & 63) == 0) { sl[wid] = l2; se[wid] = emb; }
    __syncthreads();
    if (threadIdx.x == 0) {
        float L = 0.f, Em = 0.f;
#pragma unroll
        for (int w = 0; w < THREADS / 64; ++w) { L += sl[w]; Em += se[w]; }
        partials[2 * blockIdx.x + 0] = L;
        partials[2 * blockIdx.x + 1] = Em;
    }
}

// ---------------------------------------------------------------------------
// Kernel 2: reduce per-block partials (double accumulation) -> 3 outputs.
// ---------------------------------------------------------------------------
__global__ void finalize_kernel(const float* __restrict__ partials, int nblocks,
                                float* __restrict__ out) {
    __shared__ double sl[256], se[256];
    double a = 0.0, b = 0.0;
    for (int i = threadIdx.x; i < nblocks; i += 256) {
        a += (double)partials[2 * i + 0];
        b += (double)partials[2 * i + 1];
    }
    sl[threadIdx.x] = a;
    se[threadIdx.x] = b;
    __syncthreads();
    for (int s = 128; s > 0; s >>= 1) {
        if (threadIdx.x < s) {
            sl[threadIdx.x] += sl[threadIdx.x + s];
            se[threadIdx.x] += se[threadIdx.x + s];
        }
        __syncthreads();
    }
    if (threadIdx.x == 0) {
        double sum_l2 = sl[0];
        double embd = se[0];
        double c = -0.5 * 5.0 * log(2.0 * M_PI / 10.0);
        double neg_pxz = -(c - 5.0 * sum_l2);
        out[0] = (float)(neg_pxz + embd);
        out[1] = (float)neg_pxz;
        out[2] = (float)embd;
    }
}

// ---------------------------------------------------------------------------
extern "C" void kernel_launch(void* const* d_in, const int* in_sizes, int n_in,
                              void* d_out, int out_size, void* d_ws,
                              size_t ws_size, hipStream_t stream) {
    const float* x = (const float*)d_in[0];
    const float* W1 = (const float*)d_in[1];
    const float* b1 = (const float*)d_in[2];
    const float* W2 = (const float*)d_in[3];
    const float* b2 = (const float*)d_in[4];
    const float* W3 = (const float*)d_in[5];
    const float* b3 = (const float*)d_in[6];
    const float* W4 = (const float*)d_in[7];
    const float* b4 = (const float*)d_in[8];
    const float* W5 = (const float*)d_in[9];
    const float* b5 = (const float*)d_in[10];
    const float* W6 = (const float*)d_in[11];
    const float* b6 = (const float*)d_in[12];
    const float* W7 = (const float*)d_in[13];
    const float* b7 = (const float*)d_in[14];
    const float* W8 = (const float*)d_in[15];
    const float* b8 = (const float*)d_in[16];
    const float* E = (const float*)d_in[17];

    const int nblocks = B_ROWS / THREADS;  // 512

    // ws layout
    size_t off = 0;
    float* eNormHalf = (float*)((char*)d_ws + off); off += NE * sizeof(float);
    float* scoreBuf  = (float*)((char*)d_ws + off); off += (size_t)NSLICE * B_ROWS * sizeof(float);
    int*   idxBuf    = (int*)  ((char*)d_ws + off); off += (size_t)NSLICE * B_ROWS * sizeof(int);
    float* partials  = (float*)((char*)d_ws + off); off += (size_t)nblocks * 2 * sizeof(float);

    enorm_kernel<<<(NE + THREADS - 1) / THREADS, THREADS, 0, stream>>>(E, eNormHalf);

    if (ws_size >= off) {
        dim3 grid(nblocks, NSLICE);
        scan_kernel<<<grid, THREADS, 0, stream>>>(
            x, W1, b1, W2, b2, W3, b3, W4, b4, E, eNormHalf, scoreBuf, idxBuf);
        finish_rows_kernel<<<nblocks, THREADS, 0, stream>>>(
            x, W1, b1, W2, b2, W3, b3, W4, b4, W5, b5, W6, b6, W7, b7, W8, b8,
            E, scoreBuf, idxBuf, partials);
    } else {
        // ws too small for candidate buffers: monolithic fallback
        float* partialsFB = (float*)((char*)d_ws + NE * sizeof(float));
        vqvae_main_kernel<<<nblocks, THREADS, 0, stream>>>(
            x, W1, b1, W2, b2, W3, b3, W4, b4, W5, b5, W6, b6, W7, b7, W8, b8,
            E, eNormHalf, partialsFB);
        partials = partialsFB;
    }

    finalize_kernel<<<1, 256, 0, stream>>>(partials, nblocks, (float*)d_out);
}

// Round 3
// 189.553 us; speedup vs baseline: 14.3302x; 14.3302x over previous
//
#include <hip/hip_runtime.h>
#include <math.h>

#define B_ROWS 131072
#define NE 2048
#define ZDIM 64
#define THREADS 256

typedef __attribute__((ext_vector_type(8))) short short8;
typedef __attribute__((ext_vector_type(4))) float f32x4;

// ---------------------------------------------------------------------------
// bf16 helpers (RNE), bit-exact with __float2bfloat16
// ---------------------------------------------------------------------------
static __device__ __forceinline__ unsigned short f2bf(float f) {
    unsigned int u = __float_as_uint(f);
    unsigned int r = (u + 0x7FFFu + ((u >> 16) & 1u)) >> 16;
    return (unsigned short)r;
}
static __device__ __forceinline__ float bf2f(unsigned short s) {
    return __uint_as_float(((unsigned int)s) << 16);
}

// ---------------------------------------------------------------------------
// Shared device helper: encoder (x -> z[64]), exact fp32.
// ---------------------------------------------------------------------------
__device__ __forceinline__ void encode_row(
    const float* __restrict__ xin,
    const float* __restrict__ W1, const float* __restrict__ b1,
    const float* __restrict__ W2, const float* __restrict__ b2,
    const float* __restrict__ W3, const float* __restrict__ b3,
    const float* __restrict__ W4, const float* __restrict__ b4,
    float* __restrict__ z) {
    float h1[16];
#pragma unroll
    for (int k = 0; k < 16; ++k) {
        float a = b1[k];
#pragma unroll
        for (int i = 0; i < 5; ++i) a = fmaf(xin[i], W1[i * 16 + k], a);
        h1[k] = fmaxf(a, 0.f);
    }
    float h2[32];
#pragma unroll
    for (int k = 0; k < 32; ++k) {
        float a = b2[k];
#pragma unroll
        for (int i = 0; i < 16; ++i) a = fmaf(h1[i], W2[i * 32 + k], a);
        h2[k] = fmaxf(a, 0.f);
    }
    float h3[16];
#pragma unroll
    for (int k = 0; k < 16; ++k) {
        float a = b3[k];
#pragma unroll
        for (int i = 0; i < 32; ++i) a = fmaf(h2[i], W3[i * 16 + k], a);
        h3[k] = fmaxf(a, 0.f);
    }
#pragma unroll
    for (int k = 0; k < ZDIM; ++k) {
        float a = b4[k];
#pragma unroll
        for (int i = 0; i < 16; ++i) a = fmaf(h3[i], W4[i * 64 + k], a);
        z[k] = a;
    }
}

// ---------------------------------------------------------------------------
// Kernel P: E (fp32) -> Ebf (bf16 bits) + eNormHalf = 0.5*|bf16(e)|^2 (fp32).
// Using bf16-rounded values in the norm keeps score = z.e' - 0.5|e'|^2 an
// exact distance ranking against the rounded codebook.
// ---------------------------------------------------------------------------
__global__ void prep_kernel(const float* __restrict__ E,
                            unsigned short* __restrict__ Ebf,
                            float* __restrict__ eNormHalf) {
    int j = blockIdx.x * blockDim.x + threadIdx.x;
    if (j < NE) {
        float s = 0.f;
#pragma unroll
        for (int d = 0; d < ZDIM; ++d) {
            unsigned short b = f2bf(E[j * ZDIM + d]);
            Ebf[j * ZDIM + d] = b;
            float v = bf2f(b);
            s = fmaf(v, v, s);
        }
        eNormHalf[j] = 0.5f * s;
    }
}

// fp32 norms for the fallback path (bit-exact with R1 behavior)
__global__ void enorm_kernel(const float* __restrict__ E,
                             float* __restrict__ eNormHalf) {
    int j = blockIdx.x * blockDim.x + threadIdx.x;
    if (j < NE) {
        float s = 0.f;
#pragma unroll
        for (int d = 0; d < ZDIM; ++d) {
            float v = E[j * ZDIM + d];
            s = fmaf(v, v, s);
        }
        eNormHalf[j] = 0.5f * s;
    }
}

// ---------------------------------------------------------------------------
// Kernel Z: encoder -> zbf (bf16), one thread per row.
// ---------------------------------------------------------------------------
__global__ __launch_bounds__(THREADS) void encode_kernel(
    const float* __restrict__ x,
    const float* __restrict__ W1, const float* __restrict__ b1,
    const float* __restrict__ W2, const float* __restrict__ b2,
    const float* __restrict__ W3, const float* __restrict__ b3,
    const float* __restrict__ W4, const float* __restrict__ b4,
    unsigned short* __restrict__ zbf) {
    const int row = blockIdx.x * THREADS + threadIdx.x;
    float xin[5];
#pragma unroll
    for (int i = 0; i < 5; ++i) xin[i] = x[row * 5 + i];
    float z[ZDIM];
    encode_row(xin, W1, b1, W2, b2, W3, b3, W4, b4, z);
#pragma unroll
    for (int q = 0; q < 8; ++q) {
        short8 v;
#pragma unroll
        for (int e = 0; e < 8; ++e) v[e] = (short)f2bf(z[q * 8 + e]);
        *(short8*)(zbf + row * ZDIM + q * 8) = v;
    }
}

// ---------------------------------------------------------------------------
// Kernel S: MFMA distance scan -> idxBest[row].
// Block = 4 waves, 128 rows (wave w owns rows [blk*128 + w*32, +32)).
// Ebf staged through LDS in 16 chunks of 128 cols (16 KB), XOR-swizzled so
// B-frag ds_read_b128 is ~2-way-conflict (free). A-frags (z rows) live in
// VGPRs for the whole kernel. Score = MFMA(z,E^T) - 0.5|e|^2; per-lane argmax
// then 16-lane shuffle reduce with min-index tie-break.
// MFMA D-layout (m89-verified): col = lane&15, row = (lane>>4)*4 + reg.
// A-layout: lane holds A[row = lane&15][8*(lane>>4) + e], e = 0..7 per k-half.
// B-layout: lane holds B[8*(lane>>4)+e][col = lane&15]  (= Ebf[col][k] here).
// ---------------------------------------------------------------------------
__global__ __launch_bounds__(THREADS, 4) void scan_mfma_kernel(
    const unsigned short* __restrict__ zbf,
    const unsigned short* __restrict__ Ebf,
    const float* __restrict__ eNormHalf,
    int* __restrict__ idxBest) {

    __shared__ unsigned short ebuf[128 * ZDIM];  // 16 KB, swizzled 16B slots

    const int tid = threadIdx.x;
    const int lane = tid & 63;
    const int w = tid >> 6;
    const int l15 = lane & 15;
    const int lhi = lane >> 4;
    const int rowbase = blockIdx.x * 128 + w * 32;

    // ---- A fragments: 2 m-tiles x 2 k-halves, 8 bf16 each ----
    short8 afr[2][2];
#pragma unroll
    for (int mt = 0; mt < 2; ++mt)
#pragma unroll
        for (int h = 0; h < 2; ++h)
            afr[mt][h] = *(const short8*)(zbf + (rowbase + mt * 16 + l15) * ZDIM +
                                          h * 32 + lhi * 8);

    float best[2][4];
    int bidx[2][4];
#pragma unroll
    for (int mt = 0; mt < 2; ++mt)
#pragma unroll
        for (int r = 0; r < 4; ++r) {
            best[mt][r] = -INFINITY;
            bidx[mt][r] = 0;
        }

    const f32x4* __restrict__ esrc = (const f32x4*)Ebf;  // 16B slots
    f32x4 st0, st1, st2, st3;
    // prologue: prefetch chunk 0
    st0 = esrc[0 * 256 + tid];
    st1 = esrc[1 * 256 + tid];
    st2 = esrc[2 * 256 + tid];
    st3 = esrc[3 * 256 + tid];

    for (int c = 0; c < 16; ++c) {
        __syncthreads();  // previous chunk fully consumed
        // ---- swizzled LDS write of staged regs ----
#pragma unroll
        for (int it = 0; it < 4; ++it) {
            int ci = it * 256 + tid;
            int col = ci >> 3;
            int kb = ci & 7;
            f32x4 v = (it == 0) ? st0 : (it == 1) ? st1 : (it == 2) ? st2 : st3;
            *(f32x4*)((char*)ebuf + col * 128 + ((kb ^ (col & 7)) << 4)) = v;
        }
        // ---- prefetch next chunk (hides L2 latency under compute) ----
        if (c < 15) {
            int base = (c + 1) * 1024;
            st0 = esrc[base + 0 * 256 + tid];
            st1 = esrc[base + 1 * 256 + tid];
            st2 = esrc[base + 2 * 256 + tid];
            st3 = esrc[base + 3 * 256 + tid];
        }
        __syncthreads();  // chunk c visible

        // ---- 8 col-tiles of 16 ----
#pragma unroll
        for (int t = 0; t < 8; ++t) {
            const int nl = t * 16 + l15;
            // nl&7 == l15&7 (t*16 ≡ 0 mod 8) -> per-lane-constant swizzle
            short8 b0 = *(const short8*)((const char*)ebuf + nl * 128 +
                                         ((lhi ^ (l15 & 7)) << 4));
            short8 b1 = *(const short8*)((const char*)ebuf + nl * 128 +
                                         (((4 + lhi) ^ (l15 & 7)) << 4));
            f32x4 acc0 = {0.f, 0.f, 0.f, 0.f};
            f32x4 acc1 = {0.f, 0.f, 0.f, 0.f};
            acc0 = __builtin_amdgcn_mfma_f32_16x16x32_bf16(afr[0][0], b0, acc0, 0, 0, 0);
            acc0 = __builtin_amdgcn_mfma_f32_16x16x32_bf16(afr[0][1], b1, acc0, 0, 0, 0);
            acc1 = __builtin_amdgcn_mfma_f32_16x16x32_bf16(afr[1][0], b0, acc1, 0, 0, 0);
            acc1 = __builtin_amdgcn_mfma_f32_16x16x32_bf16(afr[1][1], b1, acc1, 0, 0, 0);

            const int n = c * 128 + nl;
            const float eN = eNormHalf[n];
#pragma unroll
            for (int mt = 0; mt < 2; ++mt) {
                f32x4 A = mt ? acc1 : acc0;
#pragma unroll
                for (int r = 0; r < 4; ++r) {
                    float s = A[r] - eN;
                    if (s > best[mt][r]) {
                        best[mt][r] = s;
                        bidx[mt][r] = n;
                    }
                }
            }
        }
    }

    // ---- cross-lane reduction (16 lanes per row-group) + write ----
#pragma unroll
    for (int mt = 0; mt < 2; ++mt)
#pragma unroll
        for (int r = 0; r < 4; ++r) {
            float s = best[mt][r];
            int ix = bidx[mt][r];
#pragma unroll
            for (int off = 1; off < 16; off <<= 1) {
                float os = __shfl_xor(s, off);
                int oi = __shfl_xor(ix, off);
                bool take = (os > s) || (os == s && oi < ix);
                s = take ? os : s;
                ix = take ? oi : ix;
            }
            if (l15 == 0)
                idxBest[rowbase + mt * 16 + lhi * 4 + r] = ix;
        }
}

// ---------------------------------------------------------------------------
// Kernel F: gather z_q (fp32 E), recompute z (fp32), decoder, losses.
// ---------------------------------------------------------------------------
__global__ __launch_bounds__(THREADS) void finish_rows_kernel(
    const float* __restrict__ x,
    const float* __restrict__ W1, const float* __restrict__ b1,
    const float* __restrict__ W2, const float* __restrict__ b2,
    const float* __restrict__ W3, const float* __restrict__ b3,
    const float* __restrict__ W4, const float* __restrict__ b4,
    const float* __restrict__ W5, const float* __restrict__ b5,
    const float* __restrict__ W6, const float* __restrict__ b6,
    const float* __restrict__ W7, const float* __restrict__ b7,
    const float* __restrict__ W8, const float* __restrict__ b8,
    const float* __restrict__ E, const int* __restrict__ idxBest,
    float* __restrict__ partials) {

    const int row = blockIdx.x * THREADS + threadIdx.x;
    const int bidx = idxBest[row];

    float xin[5];
#pragma unroll
    for (int i = 0; i < 5; ++i) xin[i] = x[row * 5 + i];
    float z[ZDIM];
    encode_row(xin, W1, b1, W2, b2, W3, b3, W4, b4, z);

    float zq[ZDIM];
#pragma unroll
    for (int d = 0; d < ZDIM; ++d) zq[d] = E[bidx * ZDIM + d];

    float emb = 0.f;
#pragma unroll
    for (int d = 0; d < ZDIM; ++d) {
        float diff = z[d] - zq[d];
        emb = fmaf(diff, diff, emb);
    }
    emb *= 2.0f;  // embed + BETA*commit, BETA=1

    float g1[16];
#pragma unroll
    for (int k = 0; k < 16; ++k) {
        float a = b5[k];
#pragma unroll
        for (int i = 0; i < ZDIM; ++i) a = fmaf(zq[i], W5[i * 16 + k], a);
        g1[k] = fmaxf(a, 0.f);
    }
    float g2[32];
#pragma unroll
    for (int k = 0; k < 32; ++k) {
        float a = b6[k];
#pragma unroll
        for (int i = 0; i < 16; ++i) a = fmaf(g1[i], W6[i * 32 + k], a);
        g2[k] = fmaxf(a, 0.f);
    }
    float g3[16];
#pragma unroll
    for (int k = 0; k < 16; ++k) {
        float a = b7[k];
#pragma unroll
        for (int i = 0; i < 32; ++i) a = fmaf(g2[i], W7[i * 16 + k], a);
        g3[k] = fmaxf(a, 0.f);
    }
    float l2 = 0.f;
#pragma unroll
    for (int k = 0; k < 5; ++k) {
        float a = b8[k];
#pragma unroll
        for (int i = 0; i < 16; ++i) a = fmaf(g3[i], W8[i * 5 + k], a);
        float diff = xin[k] - a;
        l2 = fmaf(diff, diff, l2);
    }

#pragma unroll
    for (int off = 32; off > 0; off >>= 1) {
        l2 += __shfl_down(l2, off);
        emb += __shfl_down(emb, off);
    }
    __shared__ float sl[THREADS / 64], se[THREADS / 64];
    const int wid = threadIdx.x >> 6;
    if ((threadIdx.x & 63) == 0) {
        sl[wid] = l2;
        se[wid] = emb;
    }
    __syncthreads();
    if (threadIdx.x == 0) {
        float L = 0.f, Em = 0.f;
#pragma unroll
        for (int ww = 0; ww < THREADS / 64; ++ww) {
            L += sl[ww];
            Em += se[ww];
        }
        partials[2 * blockIdx.x + 0] = L;
        partials[2 * blockIdx.x + 1] = Em;
    }
}

// ---------------------------------------------------------------------------
// Fallback monolithic fp32 kernel (ws too small) — proven R1 path.
// ---------------------------------------------------------------------------
__global__ __launch_bounds__(THREADS) void vqvae_main_kernel(
    const float* __restrict__ x,
    const float* __restrict__ W1, const float* __restrict__ b1,
    const float* __restrict__ W2, const float* __restrict__ b2,
    const float* __restrict__ W3, const float* __restrict__ b3,
    const float* __restrict__ W4, const float* __restrict__ b4,
    const float* __restrict__ W5, const float* __restrict__ b5,
    const float* __restrict__ W6, const float* __restrict__ b6,
    const float* __restrict__ W7, const float* __restrict__ b7,
    const float* __restrict__ W8, const float* __restrict__ b8,
    const float* __restrict__ E, const float* __restrict__ eNormHalf,
    float* __restrict__ partials) {

    const int row = blockIdx.x * blockDim.x + threadIdx.x;
    float l2 = 0.f, emb = 0.f;

    if (row < B_ROWS) {
        float xin[5];
#pragma unroll
        for (int i = 0; i < 5; ++i) xin[i] = x[row * 5 + i];
        float z[ZDIM];
        encode_row(xin, W1, b1, W2, b2, W3, b3, W4, b4, z);

        float best = -INFINITY;
        int bidx = 0;
        const float4* __restrict__ E4 = reinterpret_cast<const float4*>(E);
        for (int j = 0; j < NE; ++j) {
            float a0 = 0.f, a1 = 0.f, a2 = 0.f, a3 = 0.f;
#pragma unroll
            for (int q = 0; q < ZDIM / 4; ++q) {
                float4 e = E4[j * (ZDIM / 4) + q];
                a0 = fmaf(z[4 * q + 0], e.x, a0);
                a1 = fmaf(z[4 * q + 1], e.y, a1);
                a2 = fmaf(z[4 * q + 2], e.z, a2);
                a3 = fmaf(z[4 * q + 3], e.w, a3);
            }
            float score = ((a0 + a1) + (a2 + a3)) - eNormHalf[j];
            if (score > best) { best = score; bidx = j; }
        }
        float zq[ZDIM];
#pragma unroll
        for (int d = 0; d < ZDIM; ++d) zq[d] = E[bidx * ZDIM + d];
#pragma unroll
        for (int d = 0; d < ZDIM; ++d) {
            float diff = z[d] - zq[d];
            emb = fmaf(diff, diff, emb);
        }
        emb *= 2.0f;
        float g1[16];
#pragma unroll
        for (int k = 0; k < 16; ++k) {
            float a = b5[k];
#pragma unroll
            for (int i = 0; i < ZDIM; ++i) a = fmaf(zq[i], W5[i * 16 + k], a);
            g1[k] = fmaxf(a, 0.f);
        }
        float g2[32];
#pragma unroll
        for (int k = 0; k < 32; ++k) {
            float a = b6[k];
#pragma unroll
            for (int i = 0; i < 16; ++i) a = fmaf(g1[i], W6[i * 32 + k], a);
            g2[k] = fmaxf(a, 0.f);
        }
        float g3[16];
#pragma unroll
        for (int k = 0; k < 16; ++k) {
            float a = b7[k];
#pragma unroll
            for (int i = 0; i < 32; ++i) a = fmaf(g2[i], W7[i * 16 + k], a);
            g3[k] = fmaxf(a, 0.f);
        }
#pragma unroll
        for (int k = 0; k < 5; ++k) {
            float a = b8[k];
#pragma unroll
            for (int i = 0; i < 16; ++i) a = fmaf(g3[i], W8[i * 5 + k], a);
            float diff = xin[k] - a;
            l2 = fmaf(diff, diff, l2);
        }
    }
#pragma unroll
    for (int off = 32; off > 0; off >>= 1) {
        l2 += __shfl_down(l2, off);
        emb += __shfl_down(emb, off);
    }
    __shared__ float sl[THREADS / 64], se[THREADS / 64];
    const int wid = threadIdx.x >> 6;
    if ((threadIdx.x & 63) == 0) { sl[wid] = l2; se[wid] = emb; }
    __syncthreads();
    if (threadIdx.x == 0) {
        float L = 0.f, Em = 0.f;
#pragma unroll
        for (int ww = 0; ww < THREADS / 64; ++ww) { L += sl[ww]; Em += se[ww]; }
        partials[2 * blockIdx.x + 0] = L;
        partials[2 * blockIdx.x + 1] = Em;
    }
}

// ---------------------------------------------------------------------------
// Final reduce: per-block partials (double accumulation) -> 3 scalars.
// ---------------------------------------------------------------------------
__global__ void finalize_kernel(const float* __restrict__ partials, int nblocks,
                                float* __restrict__ out) {
    __shared__ double sl[256], se[256];
    double a = 0.0, b = 0.0;
    for (int i = threadIdx.x; i < nblocks; i += 256) {
        a += (double)partials[2 * i + 0];
        b += (double)partials[2 * i + 1];
    }
    sl[threadIdx.x] = a;
    se[threadIdx.x] = b;
    __syncthreads();
    for (int s = 128; s > 0; s >>= 1) {
        if (threadIdx.x < s) {
            sl[threadIdx.x] += sl[threadIdx.x + s];
            se[threadIdx.x] += se[threadIdx.x + s];
        }
        __syncthreads();
    }
    if (threadIdx.x == 0) {
        double sum_l2 = sl[0];
        double embd = se[0];
        double c = -0.5 * 5.0 * log(2.0 * M_PI / 10.0);
        double neg_pxz = -(c - 5.0 * sum_l2);
        out[0] = (float)(neg_pxz + embd);
        out[1] = (float)neg_pxz;
        out[2] = (float)embd;
    }
}

// ---------------------------------------------------------------------------
extern "C" void kernel_launch(void* const* d_in, const int* in_sizes, int n_in,
                              void* d_out, int out_size, void* d_ws,
                              size_t ws_size, hipStream_t stream) {
    const float* x = (const float*)d_in[0];
    const float* W1 = (const float*)d_in[1];
    const float* b1 = (const float*)d_in[2];
    const float* W2 = (const float*)d_in[3];
    const float* b2 = (const float*)d_in[4];
    const float* W3 = (const float*)d_in[5];
    const float* b3 = (const float*)d_in[6];
    const float* W4 = (const float*)d_in[7];
    const float* b4 = (const float*)d_in[8];
    const float* W5 = (const float*)d_in[9];
    const float* b5 = (const float*)d_in[10];
    const float* W6 = (const float*)d_in[11];
    const float* b6 = (const float*)d_in[12];
    const float* W7 = (const float*)d_in[13];
    const float* b7 = (const float*)d_in[14];
    const float* W8 = (const float*)d_in[15];
    const float* b8 = (const float*)d_in[16];
    const float* E = (const float*)d_in[17];

    const int nblocks = B_ROWS / THREADS;  // 512

    // ws layout (16B-aligned segments)
    char* ws = (char*)d_ws;
    unsigned short* Ebf      = (unsigned short*)(ws + 0);            // 256 KB
    float*          eNormH   = (float*)(ws + 262144);                // 8 KB
    unsigned short* zbf      = (unsigned short*)(ws + 270336);       // 16 MB
    int*            idxBest  = (int*)(ws + 270336 + 16777216);       // 512 KB
    float*          partials = (float*)(ws + 270336 + 16777216 + 524288);
    const size_t need = 270336 + 16777216 + 524288 + (size_t)nblocks * 2 * sizeof(float);

    if (ws_size >= need) {
        prep_kernel<<<(NE + THREADS - 1) / THREADS, THREADS, 0, stream>>>(E, Ebf, eNormH);
        encode_kernel<<<nblocks, THREADS, 0, stream>>>(x, W1, b1, W2, b2, W3, b3,
                                                       W4, b4, zbf);
        scan_mfma_kernel<<<B_ROWS / 128, THREADS, 0, stream>>>(zbf, Ebf, eNormH,
                                                               idxBest);
        finish_rows_kernel<<<nblocks, THREADS, 0, stream>>>(
            x, W1, b1, W2, b2, W3, b3, W4, b4, W5, b5, W6, b6, W7, b7, W8, b8,
            E, idxBest, partials);
        finalize_kernel<<<1, 256, 0, stream>>>(partials, nblocks, (float*)d_out);
    } else {
        // fallback: proven fp32 monolithic path
        float* eNormFB = (float*)ws;                       // 8 KB
        float* partFB  = (float*)(ws + 16384);
        enorm_kernel<<<(NE + THREADS - 1) / THREADS, THREADS, 0, stream>>>(E, eNormFB);
        vqvae_main_kernel<<<nblocks, THREADS, 0, stream>>>(
            x, W1, b1, W2, b2, W3, b3, W4, b4, W5, b5, W6, b6, W7, b7, W8, b8,
            E, eNormFB, partFB);
        finalize_kernel<<<1, 256, 0, stream>>>(partFB, nblocks, (float*)d_out);
    }
}

// Round 4
// 126.764 us; speedup vs baseline: 21.4282x; 1.4953x over previous
//
#include <hip/hip_runtime.h>
#include <math.h>

#define B_ROWS 131072
#define NE 2048
#define ZDIM 64
#define THREADS 256

typedef __attribute__((ext_vector_type(8))) short short8;
typedef __attribute__((ext_vector_type(4))) float f32x4;

typedef const __attribute__((address_space(1))) void gv_t;
typedef __attribute__((address_space(3))) void lv_t;

// async global->LDS DMA, 16 B per lane. LDS dest = wave-uniform base + lane*16
// (m104); global src is per-lane (m173: pre-swizzled source pattern).
static __device__ __forceinline__ void gl_lds16(const void* g, void* l) {
    __builtin_amdgcn_global_load_lds((gv_t*)(uintptr_t)g,
                                     (lv_t*)(unsigned)(uintptr_t)l, 16, 0, 0);
}

// ---------------------------------------------------------------------------
// bf16 helpers (RNE), bit-exact with __float2bfloat16
// ---------------------------------------------------------------------------
static __device__ __forceinline__ unsigned short f2bf(float f) {
    unsigned int u = __float_as_uint(f);
    unsigned int r = (u + 0x7FFFu + ((u >> 16) & 1u)) >> 16;
    return (unsigned short)r;
}
static __device__ __forceinline__ float bf2f(unsigned short s) {
    return __uint_as_float(((unsigned int)s) << 16);
}

// ---------------------------------------------------------------------------
// Shared device helper: encoder (x -> z[64]), exact fp32.
// ---------------------------------------------------------------------------
__device__ __forceinline__ void encode_row(
    const float* __restrict__ xin,
    const float* __restrict__ W1, const float* __restrict__ b1,
    const float* __restrict__ W2, const float* __restrict__ b2,
    const float* __restrict__ W3, const float* __restrict__ b3,
    const float* __restrict__ W4, const float* __restrict__ b4,
    float* __restrict__ z) {
    float h1[16];
#pragma unroll
    for (int k = 0; k < 16; ++k) {
        float a = b1[k];
#pragma unroll
        for (int i = 0; i < 5; ++i) a = fmaf(xin[i], W1[i * 16 + k], a);
        h1[k] = fmaxf(a, 0.f);
    }
    float h2[32];
#pragma unroll
    for (int k = 0; k < 32; ++k) {
        float a = b2[k];
#pragma unroll
        for (int i = 0; i < 16; ++i) a = fmaf(h1[i], W2[i * 32 + k], a);
        h2[k] = fmaxf(a, 0.f);
    }
    float h3[16];
#pragma unroll
    for (int k = 0; k < 16; ++k) {
        float a = b3[k];
#pragma unroll
        for (int i = 0; i < 32; ++i) a = fmaf(h2[i], W3[i * 16 + k], a);
        h3[k] = fmaxf(a, 0.f);
    }
#pragma unroll
    for (int k = 0; k < ZDIM; ++k) {
        float a = b4[k];
#pragma unroll
        for (int i = 0; i < 16; ++i) a = fmaf(h3[i], W4[i * 64 + k], a);
        z[k] = a;
    }
}

// ---------------------------------------------------------------------------
// Kernel Z (fused): encoder -> zbf (bf16) for all rows; first 2048 global
// threads also prep the codebook: Ebf = bf16(E), eNormHalf = 0.5*|bf16(e)|^2.
// ---------------------------------------------------------------------------
__global__ __launch_bounds__(THREADS) void encode_prep_kernel(
    const float* __restrict__ x,
    const float* __restrict__ W1, const float* __restrict__ b1,
    const float* __restrict__ W2, const float* __restrict__ b2,
    const float* __restrict__ W3, const float* __restrict__ b3,
    const float* __restrict__ W4, const float* __restrict__ b4,
    const float* __restrict__ E,
    unsigned short* __restrict__ zbf,
    unsigned short* __restrict__ Ebf,
    float* __restrict__ eNormHalf) {
    const int row = blockIdx.x * THREADS + threadIdx.x;

    if (row < NE) {  // prep codebook (blocks 0..7 only)
        float s = 0.f;
#pragma unroll
        for (int d = 0; d < ZDIM; ++d) {
            unsigned short bb = f2bf(E[row * ZDIM + d]);
            Ebf[row * ZDIM + d] = bb;
            float v = bf2f(bb);
            s = fmaf(v, v, s);
        }
        eNormHalf[row] = 0.5f * s;
    }

    float xin[5];
#pragma unroll
    for (int i = 0; i < 5; ++i) xin[i] = x[row * 5 + i];
    float z[ZDIM];
    encode_row(xin, W1, b1, W2, b2, W3, b3, W4, b4, z);
#pragma unroll
    for (int q = 0; q < 8; ++q) {
        short8 v;
#pragma unroll
        for (int e = 0; e < 8; ++e) v[e] = (short)f2bf(z[q * 8 + e]);
        *(short8*)(zbf + row * ZDIM + q * 8) = v;
    }
}

// ---------------------------------------------------------------------------
// Kernel S: MFMA distance scan -> idxBest[row].
// Block = 4 waves, 128 rows. Ebf streamed via global_load_lds DMA (no staging
// VGPRs -> no spill), double-buffered 16 KB chunks, counted vmcnt(4) so one
// chunk's DMA flies under the previous chunk's compute. LDS layout is
// IDENTICAL to the R3-validated one: slot(col,kb) at col*128 + ((kb^(col&7))<<4),
// achieved by pre-swizzling the per-lane GLOBAL address (linear LDS write).
// eNormHalf staged to LDS once. Argmax + 16-lane reduce unchanged (validated).
// ---------------------------------------------------------------------------
__global__ __launch_bounds__(THREADS, 4) void scan_mfma_kernel(
    const unsigned short* __restrict__ zbf,
    const unsigned short* __restrict__ Ebf,
    const float* __restrict__ eNormHalf,
    int* __restrict__ idxBest) {

    __shared__ unsigned short ebuf[2][128 * ZDIM];  // 2 x 16 KB
    __shared__ float enorm[NE];                     // 8 KB

    const int tid = threadIdx.x;
    const int lane = tid & 63;
    const int w = tid >> 6;
    const int l15 = lane & 15;
    const int lhi = lane >> 4;
    const int rowbase = blockIdx.x * 128 + w * 32;

    // ---- stage eNormHalf -> LDS (8 KB) ----
    {
        const float4* es = (const float4*)eNormHalf;
        float4* ed = (float4*)enorm;
        ed[tid] = es[tid];
        ed[tid + 256] = es[tid + 256];
    }

    // ---- A fragments: 2 m-tiles x 2 k-halves ----
    short8 afr[2][2];
#pragma unroll
    for (int mt = 0; mt < 2; ++mt)
#pragma unroll
        for (int h = 0; h < 2; ++h)
            afr[mt][h] = *(const short8*)(zbf + (rowbase + mt * 16 + l15) * ZDIM +
                                          h * 32 + lhi * 8);

    float best[2][4];
    int bidx[2][4];
#pragma unroll
    for (int mt = 0; mt < 2; ++mt)
#pragma unroll
        for (int r = 0; r < 4; ++r) {
            best[mt][r] = -INFINITY;
            bidx[mt][r] = 0;
        }

    // per-lane pre-swizzled global byte offset within a chunk-row group:
    // linear LDS slot sigma = q*256 + w*64 + lane -> (col = sigma>>3, kb' = sigma&7)
    // must receive global slot (col, kb' ^ (col&7)); col&7 == lane>>3.
    const int pi = (lane >> 3) * 128 + (((lane & 7) ^ (lane >> 3)) << 4);
    const char* gb = (const char*)Ebf;

    // ---- prologue: issue DMA for chunks 0 and 1 ----
#pragma unroll
    for (int q = 0; q < 4; ++q)
        gl_lds16(gb + 0 * 16384 + q * 4096 + w * 1024 + pi,
                 (char*)&ebuf[0][0] + q * 4096 + w * 1024);
#pragma unroll
    for (int q = 0; q < 4; ++q)
        gl_lds16(gb + 1 * 16384 + q * 4096 + w * 1024 + pi,
                 (char*)&ebuf[1][0] + q * 4096 + w * 1024);

    // full drain once (also publishes the enorm ds_writes); trivial cost
    __syncthreads();

    for (int c = 0; c < 16; ++c) {
        const int cur = c & 1;
        // chunk c ready when only the newest 4 DMAs (chunk c+1) are in flight
        if (c < 15)
            asm volatile("s_waitcnt vmcnt(4)" ::: "memory");
        else
            asm volatile("s_waitcnt vmcnt(0)" ::: "memory");
        asm volatile("s_barrier" ::: "memory");

        const unsigned short* eb = &ebuf[cur][0];
#pragma unroll
        for (int t = 0; t < 8; ++t) {
            const int nl = t * 16 + l15;
            // nl&7 == l15&7 -> per-lane-constant swizzle term (R3-validated)
            short8 b0 = *(const short8*)((const char*)eb + nl * 128 +
                                         ((lhi ^ (l15 & 7)) << 4));
            short8 b1 = *(const short8*)((const char*)eb + nl * 128 +
                                         (((4 + lhi) ^ (l15 & 7)) << 4));
            f32x4 acc0 = {0.f, 0.f, 0.f, 0.f};
            f32x4 acc1 = {0.f, 0.f, 0.f, 0.f};
            acc0 = __builtin_amdgcn_mfma_f32_16x16x32_bf16(afr[0][0], b0, acc0, 0, 0, 0);
            acc0 = __builtin_amdgcn_mfma_f32_16x16x32_bf16(afr[0][1], b1, acc0, 0, 0, 0);
            acc1 = __builtin_amdgcn_mfma_f32_16x16x32_bf16(afr[1][0], b0, acc1, 0, 0, 0);
            acc1 = __builtin_amdgcn_mfma_f32_16x16x32_bf16(afr[1][1], b1, acc1, 0, 0, 0);

            const int n = c * 128 + nl;
            const float eN = enorm[n];
#pragma unroll
            for (int mt = 0; mt < 2; ++mt) {
                f32x4 A = mt ? acc1 : acc0;
#pragma unroll
                for (int r = 0; r < 4; ++r) {
                    float s = A[r] - eN;
                    if (s > best[mt][r]) {
                        best[mt][r] = s;
                        bidx[mt][r] = n;
                    }
                }
            }
        }
        // all waves done reading ebuf[cur] before DMA overwrites it
        asm volatile("s_barrier" ::: "memory");
        if (c + 2 < 16) {
#pragma unroll
            for (int q = 0; q < 4; ++q)
                gl_lds16(gb + (c + 2) * 16384 + q * 4096 + w * 1024 + pi,
                         (char*)&ebuf[cur][0] + q * 4096 + w * 1024);
        }
    }

    // ---- cross-lane reduction (16 lanes per row-group) + write ----
#pragma unroll
    for (int mt = 0; mt < 2; ++mt)
#pragma unroll
        for (int r = 0; r < 4; ++r) {
            float s = best[mt][r];
            int ix = bidx[mt][r];
#pragma unroll
            for (int off = 1; off < 16; off <<= 1) {
                float os = __shfl_xor(s, off);
                int oi = __shfl_xor(ix, off);
                bool take = (os > s) || (os == s && oi < ix);
                s = take ? os : s;
                ix = take ? oi : ix;
            }
            if (l15 == 0)
                idxBest[rowbase + mt * 16 + lhi * 4 + r] = ix;
        }
}

// ---------------------------------------------------------------------------
// Kernel F: gather z_q (fp32 E), recompute z (fp32), decoder, losses.
// ---------------------------------------------------------------------------
__global__ __launch_bounds__(THREADS) void finish_rows_kernel(
    const float* __restrict__ x,
    const float* __restrict__ W1, const float* __restrict__ b1,
    const float* __restrict__ W2, const float* __restrict__ b2,
    const float* __restrict__ W3, const float* __restrict__ b3,
    const float* __restrict__ W4, const float* __restrict__ b4,
    const float* __restrict__ W5, const float* __restrict__ b5,
    const float* __restrict__ W6, const float* __restrict__ b6,
    const float* __restrict__ W7, const float* __restrict__ b7,
    const float* __restrict__ W8, const float* __restrict__ b8,
    const float* __restrict__ E, const int* __restrict__ idxBest,
    float* __restrict__ partials) {

    const int row = blockIdx.x * THREADS + threadIdx.x;
    const int bidx = idxBest[row];

    float xin[5];
#pragma unroll
    for (int i = 0; i < 5; ++i) xin[i] = x[row * 5 + i];
    float z[ZDIM];
    encode_row(xin, W1, b1, W2, b2, W3, b3, W4, b4, z);

    float zq[ZDIM];
#pragma unroll
    for (int d = 0; d < ZDIM; ++d) zq[d] = E[bidx * ZDIM + d];

    float emb = 0.f;
#pragma unroll
    for (int d = 0; d < ZDIM; ++d) {
        float diff = z[d] - zq[d];
        emb = fmaf(diff, diff, emb);
    }
    emb *= 2.0f;  // embed + BETA*commit, BETA=1

    float g1[16];
#pragma unroll
    for (int k = 0; k < 16; ++k) {
        float a = b5[k];
#pragma unroll
        for (int i = 0; i < ZDIM; ++i) a = fmaf(zq[i], W5[i * 16 + k], a);
        g1[k] = fmaxf(a, 0.f);
    }
    float g2[32];
#pragma unroll
    for (int k = 0; k < 32; ++k) {
        float a = b6[k];
#pragma unroll
        for (int i = 0; i < 16; ++i) a = fmaf(g1[i], W6[i * 32 + k], a);
        g2[k] = fmaxf(a, 0.f);
    }
    float g3[16];
#pragma unroll
    for (int k = 0; k < 16; ++k) {
        float a = b7[k];
#pragma unroll
        for (int i = 0; i < 32; ++i) a = fmaf(g2[i], W7[i * 16 + k], a);
        g3[k] = fmaxf(a, 0.f);
    }
    float l2 = 0.f;
#pragma unroll
    for (int k = 0; k < 5; ++k) {
        float a = b8[k];
#pragma unroll
        for (int i = 0; i < 16; ++i) a = fmaf(g3[i], W8[i * 5 + k], a);
        float diff = xin[k] - a;
        l2 = fmaf(diff, diff, l2);
    }

#pragma unroll
    for (int off = 32; off > 0; off >>= 1) {
        l2 += __shfl_down(l2, off);
        emb += __shfl_down(emb, off);
    }
    __shared__ float sl[THREADS / 64], se[THREADS / 64];
    const int wid = threadIdx.x >> 6;
    if ((threadIdx.x & 63) == 0) {
        sl[wid] = l2;
        se[wid] = emb;
    }
    __syncthreads();
    if (threadIdx.x == 0) {
        float L = 0.f, Em = 0.f;
#pragma unroll
        for (int ww = 0; ww < THREADS / 64; ++ww) {
            L += sl[ww];
            Em += se[ww];
        }
        partials[2 * blockIdx.x + 0] = L;
        partials[2 * blockIdx.x + 1] = Em;
    }
}

// ---------------------------------------------------------------------------
// Fallback path kernels (ws too small) — proven R1 monolithic fp32.
// ---------------------------------------------------------------------------
__global__ void enorm_kernel(const float* __restrict__ E,
                             float* __restrict__ eNormHalf) {
    int j = blockIdx.x * blockDim.x + threadIdx.x;
    if (j < NE) {
        float s = 0.f;
#pragma unroll
        for (int d = 0; d < ZDIM; ++d) {
            float v = E[j * ZDIM + d];
            s = fmaf(v, v, s);
        }
        eNormHalf[j] = 0.5f * s;
    }
}

__global__ __launch_bounds__(THREADS) void vqvae_main_kernel(
    const float* __restrict__ x,
    const float* __restrict__ W1, const float* __restrict__ b1,
    const float* __restrict__ W2, const float* __restrict__ b2,
    const float* __restrict__ W3, const float* __restrict__ b3,
    const float* __restrict__ W4, const float* __restrict__ b4,
    const float* __restrict__ W5, const float* __restrict__ b5,
    const float* __restrict__ W6, const float* __restrict__ b6,
    const float* __restrict__ W7, const float* __restrict__ b7,
    const float* __restrict__ W8, const float* __restrict__ b8,
    const float* __restrict__ E, const float* __restrict__ eNormHalf,
    float* __restrict__ partials) {

    const int row = blockIdx.x * blockDim.x + threadIdx.x;
    float l2 = 0.f, emb = 0.f;

    if (row < B_ROWS) {
        float xin[5];
#pragma unroll
        for (int i = 0; i < 5; ++i) xin[i] = x[row * 5 + i];
        float z[ZDIM];
        encode_row(xin, W1, b1, W2, b2, W3, b3, W4, b4, z);

        float best = -INFINITY;
        int bidx = 0;
        const float4* __restrict__ E4 = reinterpret_cast<const float4*>(E);
        for (int j = 0; j < NE; ++j) {
            float a0 = 0.f, a1 = 0.f, a2 = 0.f, a3 = 0.f;
#pragma unroll
            for (int q = 0; q < ZDIM / 4; ++q) {
                float4 e = E4[j * (ZDIM / 4) + q];
                a0 = fmaf(z[4 * q + 0], e.x, a0);
                a1 = fmaf(z[4 * q + 1], e.y, a1);
                a2 = fmaf(z[4 * q + 2], e.z, a2);
                a3 = fmaf(z[4 * q + 3], e.w, a3);
            }
            float score = ((a0 + a1) + (a2 + a3)) - eNormHalf[j];
            if (score > best) { best = score; bidx = j; }
        }
        float zq[ZDIM];
#pragma unroll
        for (int d = 0; d < ZDIM; ++d) zq[d] = E[bidx * ZDIM + d];
#pragma unroll
        for (int d = 0; d < ZDIM; ++d) {
            float diff = z[d] - zq[d];
            emb = fmaf(diff, diff, emb);
        }
        emb *= 2.0f;
        float g1[16];
#pragma unroll
        for (int k = 0; k < 16; ++k) {
            float a = b5[k];
#pragma unroll
            for (int i = 0; i < ZDIM; ++i) a = fmaf(zq[i], W5[i * 16 + k], a);
            g1[k] = fmaxf(a, 0.f);
        }
        float g2[32];
#pragma unroll
        for (int k = 0; k < 32; ++k) {
            float a = b6[k];
#pragma unroll
            for (int i = 0; i < 16; ++i) a = fmaf(g1[i], W6[i * 32 + k], a);
            g2[k] = fmaxf(a, 0.f);
        }
        float g3[16];
#pragma unroll
        for (int k = 0; k < 16; ++k) {
            float a = b7[k];
#pragma unroll
            for (int i = 0; i < 32; ++i) a = fmaf(g2[i], W7[i * 16 + k], a);
            g3[k] = fmaxf(a, 0.f);
        }
#pragma unroll
        for (int k = 0; k < 5; ++k) {
            float a = b8[k];
#pragma unroll
            for (int i = 0; i < 16; ++i) a = fmaf(g3[i], W8[i * 5 + k], a);
            float diff = xin[k] - a;
            l2 = fmaf(diff, diff, l2);
        }
    }
#pragma unroll
    for (int off = 32; off > 0; off >>= 1) {
        l2 += __shfl_down(l2, off);
        emb += __shfl_down(emb, off);
    }
    __shared__ float sl[THREADS / 64], se[THREADS / 64];
    const int wid = threadIdx.x >> 6;
    if ((threadIdx.x & 63) == 0) { sl[wid] = l2; se[wid] = emb; }
    __syncthreads();
    if (threadIdx.x == 0) {
        float L = 0.f, Em = 0.f;
#pragma unroll
        for (int ww = 0; ww < THREADS / 64; ++ww) { L += sl[ww]; Em += se[ww]; }
        partials[2 * blockIdx.x + 0] = L;
        partials[2 * blockIdx.x + 1] = Em;
    }
}

// ---------------------------------------------------------------------------
// Final reduce: per-block partials (double accumulation) -> 3 scalars.
// ---------------------------------------------------------------------------
__global__ void finalize_kernel(const float* __restrict__ partials, int nblocks,
                                float* __restrict__ out) {
    __shared__ double sl[256], se[256];
    double a = 0.0, b = 0.0;
    for (int i = threadIdx.x; i < nblocks; i += 256) {
        a += (double)partials[2 * i + 0];
        b += (double)partials[2 * i + 1];
    }
    sl[threadIdx.x] = a;
    se[threadIdx.x] = b;
    __syncthreads();
    for (int s = 128; s > 0; s >>= 1) {
        if (threadIdx.x < s) {
            sl[threadIdx.x] += sl[threadIdx.x + s];
            se[threadIdx.x] += se[threadIdx.x + s];
        }
        __syncthreads();
    }
    if (threadIdx.x == 0) {
        double sum_l2 = sl[0];
        double embd = se[0];
        double c = -0.5 * 5.0 * log(2.0 * M_PI / 10.0);
        double neg_pxz = -(c - 5.0 * sum_l2);
        out[0] = (float)(neg_pxz + embd);
        out[1] = (float)neg_pxz;
        out[2] = (float)embd;
    }
}

// ---------------------------------------------------------------------------
extern "C" void kernel_launch(void* const* d_in, const int* in_sizes, int n_in,
                              void* d_out, int out_size, void* d_ws,
                              size_t ws_size, hipStream_t stream) {
    const float* x = (const float*)d_in[0];
    const float* W1 = (const float*)d_in[1];
    const float* b1 = (const float*)d_in[2];
    const float* W2 = (const float*)d_in[3];
    const float* b2 = (const float*)d_in[4];
    const float* W3 = (const float*)d_in[5];
    const float* b3 = (const float*)d_in[6];
    const float* W4 = (const float*)d_in[7];
    const float* b4 = (const float*)d_in[8];
    const float* W5 = (const float*)d_in[9];
    const float* b5 = (const float*)d_in[10];
    const float* W6 = (const float*)d_in[11];
    const float* b6 = (const float*)d_in[12];
    const float* W7 = (const float*)d_in[13];
    const float* b7 = (const float*)d_in[14];
    const float* W8 = (const float*)d_in[15];
    const float* b8 = (const float*)d_in[16];
    const float* E = (const float*)d_in[17];

    const int nblocks = B_ROWS / THREADS;  // 512

    // ws layout (16B-aligned segments)
    char* ws = (char*)d_ws;
    unsigned short* Ebf      = (unsigned short*)(ws + 0);            // 256 KB
    float*          eNormH   = (float*)(ws + 262144);                // 8 KB
    unsigned short* zbf      = (unsigned short*)(ws + 270336);       // 16 MB
    int*            idxBest  = (int*)(ws + 270336 + 16777216);       // 512 KB
    float*          partials = (float*)(ws + 270336 + 16777216 + 524288);
    const size_t need = 270336 + 16777216 + 524288 + (size_t)nblocks * 2 * sizeof(float);

    if (ws_size >= need) {
        encode_prep_kernel<<<nblocks, THREADS, 0, stream>>>(
            x, W1, b1, W2, b2, W3, b3, W4, b4, E, zbf, Ebf, eNormH);
        scan_mfma_kernel<<<B_ROWS / 128, THREADS, 0, stream>>>(zbf, Ebf, eNormH,
                                                               idxBest);
        finish_rows_kernel<<<nblocks, THREADS, 0, stream>>>(
            x, W1, b1, W2, b2, W3, b3, W4, b4, W5, b5, W6, b6, W7, b7, W8, b8,
            E, idxBest, partials);
        finalize_kernel<<<1, 256, 0, stream>>>(partials, nblocks, (float*)d_out);
    } else {
        // fallback: proven fp32 monolithic path
        float* eNormFB = (float*)ws;                       // 8 KB
        float* partFB  = (float*)(ws + 16384);
        enorm_kernel<<<(NE + THREADS - 1) / THREADS, THREADS, 0, stream>>>(E, eNormFB);
        vqvae_main_kernel<<<nblocks, THREADS, 0, stream>>>(
            x, W1, b1, W2, b2, W3, b3, W4, b4, W5, b5, W6, b6, W7, b7, W8, b8,
            E, eNormFB, partFB);
        finalize_kernel<<<1, 256, 0, stream>>>(partFB, nblocks, (float*)d_out);
    }
}

// Round 5
// 100.774 us; speedup vs baseline: 26.9546x; 1.2579x over previous
//
#include <hip/hip_runtime.h>
#include <math.h>

#define B_ROWS 131072
#define NE 2048
#define ZDIM 64
#define THREADS 256

typedef __attribute__((ext_vector_type(8))) short short8;
typedef __attribute__((ext_vector_type(4))) float f32x4;

typedef const __attribute__((address_space(1))) void gv_t;
typedef __attribute__((address_space(3))) void lv_t;

// async global->LDS DMA, 16 B per lane. LDS dest = wave-uniform base + lane*16
// (m104); global src is per-lane (m173: pre-swizzled source pattern).
static __device__ __forceinline__ void gl_lds16(const void* g, void* l) {
    __builtin_amdgcn_global_load_lds((gv_t*)(uintptr_t)g,
                                     (lv_t*)(unsigned)(uintptr_t)l, 16, 0, 0);
}

// ---------------------------------------------------------------------------
// bf16 helpers (RNE), bit-exact with __float2bfloat16
// ---------------------------------------------------------------------------
static __device__ __forceinline__ unsigned short f2bf(float f) {
    unsigned int u = __float_as_uint(f);
    unsigned int r = (u + 0x7FFFu + ((u >> 16) & 1u)) >> 16;
    return (unsigned short)r;
}
static __device__ __forceinline__ float bf2f(unsigned short s) {
    return __uint_as_float(((unsigned int)s) << 16);
}

// ---------------------------------------------------------------------------
// Shared device helper: encoder (x -> z[64]), exact fp32.
// ---------------------------------------------------------------------------
__device__ __forceinline__ void encode_row(
    const float* __restrict__ xin,
    const float* __restrict__ W1, const float* __restrict__ b1,
    const float* __restrict__ W2, const float* __restrict__ b2,
    const float* __restrict__ W3, const float* __restrict__ b3,
    const float* __restrict__ W4, const float* __restrict__ b4,
    float* __restrict__ z) {
    float h1[16];
#pragma unroll
    for (int k = 0; k < 16; ++k) {
        float a = b1[k];
#pragma unroll
        for (int i = 0; i < 5; ++i) a = fmaf(xin[i], W1[i * 16 + k], a);
        h1[k] = fmaxf(a, 0.f);
    }
    float h2[32];
#pragma unroll
    for (int k = 0; k < 32; ++k) {
        float a = b2[k];
#pragma unroll
        for (int i = 0; i < 16; ++i) a = fmaf(h1[i], W2[i * 32 + k], a);
        h2[k] = fmaxf(a, 0.f);
    }
    float h3[16];
#pragma unroll
    for (int k = 0; k < 16; ++k) {
        float a = b3[k];
#pragma unroll
        for (int i = 0; i < 32; ++i) a = fmaf(h2[i], W3[i * 16 + k], a);
        h3[k] = fmaxf(a, 0.f);
    }
#pragma unroll
    for (int k = 0; k < ZDIM; ++k) {
        float a = b4[k];
#pragma unroll
        for (int i = 0; i < 16; ++i) a = fmaf(h3[i], W4[i * 64 + k], a);
        z[k] = a;
    }
}

// ---------------------------------------------------------------------------
// Kernel Z (fused): encoder -> zbf (bf16) for all rows; first 2048 global
// threads also prep the codebook: Ebf = bf16(E), eNormHalf = 0.5*|bf16(e)|^2.
// ---------------------------------------------------------------------------
__global__ __launch_bounds__(THREADS) void encode_prep_kernel(
    const float* __restrict__ x,
    const float* __restrict__ W1, const float* __restrict__ b1,
    const float* __restrict__ W2, const float* __restrict__ b2,
    const float* __restrict__ W3, const float* __restrict__ b3,
    const float* __restrict__ W4, const float* __restrict__ b4,
    const float* __restrict__ E,
    unsigned short* __restrict__ zbf,
    unsigned short* __restrict__ Ebf,
    float* __restrict__ eNormHalf) {
    const int row = blockIdx.x * THREADS + threadIdx.x;

    if (row < NE) {  // prep codebook (blocks 0..7 only)
        float s = 0.f;
#pragma unroll
        for (int d = 0; d < ZDIM; ++d) {
            unsigned short bb = f2bf(E[row * ZDIM + d]);
            Ebf[row * ZDIM + d] = bb;
            float v = bf2f(bb);
            s = fmaf(v, v, s);
        }
        eNormHalf[row] = 0.5f * s;
    }

    float xin[5];
#pragma unroll
    for (int i = 0; i < 5; ++i) xin[i] = x[row * 5 + i];
    float z[ZDIM];
    encode_row(xin, W1, b1, W2, b2, W3, b3, W4, b4, z);
#pragma unroll
    for (int q = 0; q < 8; ++q) {
        short8 v;
#pragma unroll
        for (int e = 0; e < 8; ++e) v[e] = (short)f2bf(z[q * 8 + e]);
        *(short8*)(zbf + row * ZDIM + q * 8) = v;
    }
}

// ---------------------------------------------------------------------------
// Kernel S: MFMA distance scan -> idxBest[row].
// Block = 4 waves, 128 rows. Ebf streamed via global_load_lds DMA,
// double-buffered 16 KB chunks, counted vmcnt(4). LDS layout identical to the
// R3/R4-validated swizzle (pre-swizzled GLOBAL source, linear LDS write).
// eNormHalf staged to LDS (lgkmcnt domain — keeps the vmcnt counter clean for
// the DMA prefetch arithmetic).
// R5 change: __launch_bounds__(256,2) instead of (256,4). LDS (40KB -> 4
// blocks/CU) already caps occupancy at 4 waves/SIMD, so the old 128-VGPR cap
// bought nothing; the compiler was snapping to the 64-VGPR step and spilling
// the pipelined ds_read results to scratch (the ~100MB/launch HBM writes).
// ---------------------------------------------------------------------------
__global__ __launch_bounds__(THREADS, 2) void scan_mfma_kernel(
    const unsigned short* __restrict__ zbf,
    const unsigned short* __restrict__ Ebf,
    const float* __restrict__ eNormHalf,
    int* __restrict__ idxBest) {

    __shared__ unsigned short ebuf[2][128 * ZDIM];  // 2 x 16 KB
    __shared__ float enorm[NE];                     // 8 KB

    const int tid = threadIdx.x;
    const int lane = tid & 63;
    const int w = tid >> 6;
    const int l15 = lane & 15;
    const int lhi = lane >> 4;
    const int rowbase = blockIdx.x * 128 + w * 32;

    // ---- stage eNormHalf -> LDS (8 KB) ----
    {
        const float4* es = (const float4*)eNormHalf;
        float4* ed = (float4*)enorm;
        ed[tid] = es[tid];
        ed[tid + 256] = es[tid + 256];
    }

    // ---- A fragments: 2 m-tiles x 2 k-halves ----
    short8 afr[2][2];
#pragma unroll
    for (int mt = 0; mt < 2; ++mt)
#pragma unroll
        for (int h = 0; h < 2; ++h)
            afr[mt][h] = *(const short8*)(zbf + (rowbase + mt * 16 + l15) * ZDIM +
                                          h * 32 + lhi * 8);

    float best[2][4];
    int bidx[2][4];
#pragma unroll
    for (int mt = 0; mt < 2; ++mt)
#pragma unroll
        for (int r = 0; r < 4; ++r) {
            best[mt][r] = -INFINITY;
            bidx[mt][r] = 0;
        }

    // per-lane pre-swizzled global byte offset within a chunk-row group:
    // linear LDS slot sigma = q*256 + w*64 + lane -> (col = sigma>>3, kb' = sigma&7)
    // must receive global slot (col, kb' ^ (col&7)); col&7 == lane>>3.
    const int pi = (lane >> 3) * 128 + (((lane & 7) ^ (lane >> 3)) << 4);
    const char* gb = (const char*)Ebf;

    // ---- prologue: issue DMA for chunks 0 and 1 ----
#pragma unroll
    for (int q = 0; q < 4; ++q)
        gl_lds16(gb + 0 * 16384 + q * 4096 + w * 1024 + pi,
                 (char*)&ebuf[0][0] + q * 4096 + w * 1024);
#pragma unroll
    for (int q = 0; q < 4; ++q)
        gl_lds16(gb + 1 * 16384 + q * 4096 + w * 1024 + pi,
                 (char*)&ebuf[1][0] + q * 4096 + w * 1024);

    // full drain once (also publishes the enorm ds_writes); trivial cost
    __syncthreads();

    for (int c = 0; c < 16; ++c) {
        const int cur = c & 1;
        // chunk c ready when only the newest 4 DMAs (chunk c+1) are in flight
        if (c < 15)
            asm volatile("s_waitcnt vmcnt(4)" ::: "memory");
        else
            asm volatile("s_waitcnt vmcnt(0)" ::: "memory");
        asm volatile("s_barrier" ::: "memory");

        const unsigned short* eb = &ebuf[cur][0];
#pragma unroll
        for (int t = 0; t < 8; ++t) {
            const int nl = t * 16 + l15;
            // nl&7 == l15&7 -> per-lane-constant swizzle term (R3-validated)
            short8 b0 = *(const short8*)((const char*)eb + nl * 128 +
                                         ((lhi ^ (l15 & 7)) << 4));
            short8 b1 = *(const short8*)((const char*)eb + nl * 128 +
                                         (((4 + lhi) ^ (l15 & 7)) << 4));
            f32x4 acc0 = {0.f, 0.f, 0.f, 0.f};
            f32x4 acc1 = {0.f, 0.f, 0.f, 0.f};
            acc0 = __builtin_amdgcn_mfma_f32_16x16x32_bf16(afr[0][0], b0, acc0, 0, 0, 0);
            acc0 = __builtin_amdgcn_mfma_f32_16x16x32_bf16(afr[0][1], b1, acc0, 0, 0, 0);
            acc1 = __builtin_amdgcn_mfma_f32_16x16x32_bf16(afr[1][0], b0, acc1, 0, 0, 0);
            acc1 = __builtin_amdgcn_mfma_f32_16x16x32_bf16(afr[1][1], b1, acc1, 0, 0, 0);

            const int n = c * 128 + nl;
            const float eN = enorm[n];
#pragma unroll
            for (int mt = 0; mt < 2; ++mt) {
                f32x4 A = mt ? acc1 : acc0;
#pragma unroll
                for (int r = 0; r < 4; ++r) {
                    float s = A[r] - eN;
                    if (s > best[mt][r]) {
                        best[mt][r] = s;
                        bidx[mt][r] = n;
                    }
                }
            }
        }
        // all waves done reading ebuf[cur] before DMA overwrites it
        asm volatile("s_barrier" ::: "memory");
        if (c + 2 < 16) {
#pragma unroll
            for (int q = 0; q < 4; ++q)
                gl_lds16(gb + (c + 2) * 16384 + q * 4096 + w * 1024 + pi,
                         (char*)&ebuf[cur][0] + q * 4096 + w * 1024);
        }
    }

    // ---- cross-lane reduction (16 lanes per row-group) + write ----
#pragma unroll
    for (int mt = 0; mt < 2; ++mt)
#pragma unroll
        for (int r = 0; r < 4; ++r) {
            float s = best[mt][r];
            int ix = bidx[mt][r];
#pragma unroll
            for (int off = 1; off < 16; off <<= 1) {
                float os = __shfl_xor(s, off);
                int oi = __shfl_xor(ix, off);
                bool take = (os > s) || (os == s && oi < ix);
                s = take ? os : s;
                ix = take ? oi : ix;
            }
            if (l15 == 0)
                idxBest[rowbase + mt * 16 + lhi * 4 + r] = ix;
        }
}

// ---------------------------------------------------------------------------
// Kernel F: gather z_q (fp32 E), recompute z (fp32), decoder, losses.
// ---------------------------------------------------------------------------
__global__ __launch_bounds__(THREADS) void finish_rows_kernel(
    const float* __restrict__ x,
    const float* __restrict__ W1, const float* __restrict__ b1,
    const float* __restrict__ W2, const float* __restrict__ b2,
    const float* __restrict__ W3, const float* __restrict__ b3,
    const float* __restrict__ W4, const float* __restrict__ b4,
    const float* __restrict__ W5, const float* __restrict__ b5,
    const float* __restrict__ W6, const float* __restrict__ b6,
    const float* __restrict__ W7, const float* __restrict__ b7,
    const float* __restrict__ W8, const float* __restrict__ b8,
    const float* __restrict__ E, const int* __restrict__ idxBest,
    float* __restrict__ partials) {

    const int row = blockIdx.x * THREADS + threadIdx.x;
    const int bidx = idxBest[row];

    float xin[5];
#pragma unroll
    for (int i = 0; i < 5; ++i) xin[i] = x[row * 5 + i];
    float z[ZDIM];
    encode_row(xin, W1, b1, W2, b2, W3, b3, W4, b4, z);

    float zq[ZDIM];
#pragma unroll
    for (int d = 0; d < ZDIM; ++d) zq[d] = E[bidx * ZDIM + d];

    float emb = 0.f;
#pragma unroll
    for (int d = 0; d < ZDIM; ++d) {
        float diff = z[d] - zq[d];
        emb = fmaf(diff, diff, emb);
    }
    emb *= 2.0f;  // embed + BETA*commit, BETA=1

    float g1[16];
#pragma unroll
    for (int k = 0; k < 16; ++k) {
        float a = b5[k];
#pragma unroll
        for (int i = 0; i < ZDIM; ++i) a = fmaf(zq[i], W5[i * 16 + k], a);
        g1[k] = fmaxf(a, 0.f);
    }
    float g2[32];
#pragma unroll
    for (int k = 0; k < 32; ++k) {
        float a = b6[k];
#pragma unroll
        for (int i = 0; i < 16; ++i) a = fmaf(g1[i], W6[i * 32 + k], a);
        g2[k] = fmaxf(a, 0.f);
    }
    float g3[16];
#pragma unroll
    for (int k = 0; k < 16; ++k) {
        float a = b7[k];
#pragma unroll
        for (int i = 0; i < 32; ++i) a = fmaf(g2[i], W7[i * 16 + k], a);
        g3[k] = fmaxf(a, 0.f);
    }
    float l2 = 0.f;
#pragma unroll
    for (int k = 0; k < 5; ++k) {
        float a = b8[k];
#pragma unroll
        for (int i = 0; i < 16; ++i) a = fmaf(g3[i], W8[i * 5 + k], a);
        float diff = xin[k] - a;
        l2 = fmaf(diff, diff, l2);
    }

#pragma unroll
    for (int off = 32; off > 0; off >>= 1) {
        l2 += __shfl_down(l2, off);
        emb += __shfl_down(emb, off);
    }
    __shared__ float sl[THREADS / 64], se[THREADS / 64];
    const int wid = threadIdx.x >> 6;
    if ((threadIdx.x & 63) == 0) {
        sl[wid] = l2;
        se[wid] = emb;
    }
    __syncthreads();
    if (threadIdx.x == 0) {
        float L = 0.f, Em = 0.f;
#pragma unroll
        for (int ww = 0; ww < THREADS / 64; ++ww) {
            L += sl[ww];
            Em += se[ww];
        }
        partials[2 * blockIdx.x + 0] = L;
        partials[2 * blockIdx.x + 1] = Em;
    }
}

// ---------------------------------------------------------------------------
// Fallback path kernels (ws too small) — proven R1 monolithic fp32.
// ---------------------------------------------------------------------------
__global__ void enorm_kernel(const float* __restrict__ E,
                             float* __restrict__ eNormHalf) {
    int j = blockIdx.x * blockDim.x + threadIdx.x;
    if (j < NE) {
        float s = 0.f;
#pragma unroll
        for (int d = 0; d < ZDIM; ++d) {
            float v = E[j * ZDIM + d];
            s = fmaf(v, v, s);
        }
        eNormHalf[j] = 0.5f * s;
    }
}

__global__ __launch_bounds__(THREADS) void vqvae_main_kernel(
    const float* __restrict__ x,
    const float* __restrict__ W1, const float* __restrict__ b1,
    const float* __restrict__ W2, const float* __restrict__ b2,
    const float* __restrict__ W3, const float* __restrict__ b3,
    const float* __restrict__ W4, const float* __restrict__ b4,
    const float* __restrict__ W5, const float* __restrict__ b5,
    const float* __restrict__ W6, const float* __restrict__ b6,
    const float* __restrict__ W7, const float* __restrict__ b7,
    const float* __restrict__ W8, const float* __restrict__ b8,
    const float* __restrict__ E, const float* __restrict__ eNormHalf,
    float* __restrict__ partials) {

    const int row = blockIdx.x * blockDim.x + threadIdx.x;
    float l2 = 0.f, emb = 0.f;

    if (row < B_ROWS) {
        float xin[5];
#pragma unroll
        for (int i = 0; i < 5; ++i) xin[i] = x[row * 5 + i];
        float z[ZDIM];
        encode_row(xin, W1, b1, W2, b2, W3, b3, W4, b4, z);

        float best = -INFINITY;
        int bidx = 0;
        const float4* __restrict__ E4 = reinterpret_cast<const float4*>(E);
        for (int j = 0; j < NE; ++j) {
            float a0 = 0.f, a1 = 0.f, a2 = 0.f, a3 = 0.f;
#pragma unroll
            for (int q = 0; q < ZDIM / 4; ++q) {
                float4 e = E4[j * (ZDIM / 4) + q];
                a0 = fmaf(z[4 * q + 0], e.x, a0);
                a1 = fmaf(z[4 * q + 1], e.y, a1);
                a2 = fmaf(z[4 * q + 2], e.z, a2);
                a3 = fmaf(z[4 * q + 3], e.w, a3);
            }
            float score = ((a0 + a1) + (a2 + a3)) - eNormHalf[j];
            if (score > best) { best = score; bidx = j; }
        }
        float zq[ZDIM];
#pragma unroll
        for (int d = 0; d < ZDIM; ++d) zq[d] = E[bidx * ZDIM + d];
#pragma unroll
        for (int d = 0; d < ZDIM; ++d) {
            float diff = z[d] - zq[d];
            emb = fmaf(diff, diff, emb);
        }
        emb *= 2.0f;
        float g1[16];
#pragma unroll
        for (int k = 0; k < 16; ++k) {
            float a = b5[k];
#pragma unroll
            for (int i = 0; i < ZDIM; ++i) a = fmaf(zq[i], W5[i * 16 + k], a);
            g1[k] = fmaxf(a, 0.f);
        }
        float g2[32];
#pragma unroll
        for (int k = 0; k < 32; ++k) {
            float a = b6[k];
#pragma unroll
            for (int i = 0; i < 16; ++i) a = fmaf(g1[i], W6[i * 32 + k], a);
            g2[k] = fmaxf(a, 0.f);
        }
        float g3[16];
#pragma unroll
        for (int k = 0; k < 16; ++k) {
            float a = b7[k];
#pragma unroll
            for (int i = 0; i < 32; ++i) a = fmaf(g2[i], W7[i * 16 + k], a);
            g3[k] = fmaxf(a, 0.f);
        }
#pragma unroll
        for (int k = 0; k < 5; ++k) {
            float a = b8[k];
#pragma unroll
            for (int i = 0; i < 16; ++i) a = fmaf(g3[i], W8[i * 5 + k], a);
            float diff = xin[k] - a;
            l2 = fmaf(diff, diff, l2);
        }
    }
#pragma unroll
    for (int off = 32; off > 0; off >>= 1) {
        l2 += __shfl_down(l2, off);
        emb += __shfl_down(emb, off);
    }
    __shared__ float sl[THREADS / 64], se[THREADS / 64];
    const int wid = threadIdx.x >> 6;
    if ((threadIdx.x & 63) == 0) { sl[wid] = l2; se[wid] = emb; }
    __syncthreads();
    if (threadIdx.x == 0) {
        float L = 0.f, Em = 0.f;
#pragma unroll
        for (int ww = 0; ww < THREADS / 64; ++ww) { L += sl[ww]; Em += se[ww]; }
        partials[2 * blockIdx.x + 0] = L;
        partials[2 * blockIdx.x + 1] = Em;
    }
}

// ---------------------------------------------------------------------------
// Final reduce: per-block partials (double accumulation) -> 3 scalars.
// ---------------------------------------------------------------------------
__global__ void finalize_kernel(const float* __restrict__ partials, int nblocks,
                                float* __restrict__ out) {
    __shared__ double sl[256], se[256];
    double a = 0.0, b = 0.0;
    for (int i = threadIdx.x; i < nblocks; i += 256) {
        a += (double)partials[2 * i + 0];
        b += (double)partials[2 * i + 1];
    }
    sl[threadIdx.x] = a;
    se[threadIdx.x] = b;
    __syncthreads();
    for (int s = 128; s > 0; s >>= 1) {
        if (threadIdx.x < s) {
            sl[threadIdx.x] += sl[threadIdx.x + s];
            se[threadIdx.x] += se[threadIdx.x + s];
        }
        __syncthreads();
    }
    if (threadIdx.x == 0) {
        double sum_l2 = sl[0];
        double embd = se[0];
        double c = -0.5 * 5.0 * log(2.0 * M_PI / 10.0);
        double neg_pxz = -(c - 5.0 * sum_l2);
        out[0] = (float)(neg_pxz + embd);
        out[1] = (float)neg_pxz;
        out[2] = (float)embd;
    }
}

// ---------------------------------------------------------------------------
extern "C" void kernel_launch(void* const* d_in, const int* in_sizes, int n_in,
                              void* d_out, int out_size, void* d_ws,
                              size_t ws_size, hipStream_t stream) {
    const float* x = (const float*)d_in[0];
    const float* W1 = (const float*)d_in[1];
    const float* b1 = (const float*)d_in[2];
    const float* W2 = (const float*)d_in[3];
    const float* b2 = (const float*)d_in[4];
    const float* W3 = (const float*)d_in[5];
    const float* b3 = (const float*)d_in[6];
    const float* W4 = (const float*)d_in[7];
    const float* b4 = (const float*)d_in[8];
    const float* W5 = (const float*)d_in[9];
    const float* b5 = (const float*)d_in[10];
    const float* W6 = (const float*)d_in[11];
    const float* b6 = (const float*)d_in[12];
    const float* W7 = (const float*)d_in[13];
    const float* b7 = (const float*)d_in[14];
    const float* W8 = (const float*)d_in[15];
    const float* b8 = (const float*)d_in[16];
    const float* E = (const float*)d_in[17];

    const int nblocks = B_ROWS / THREADS;  // 512

    // ws layout (16B-aligned segments)
    char* ws = (char*)d_ws;
    unsigned short* Ebf      = (unsigned short*)(ws + 0);            // 256 KB
    float*          eNormH   = (float*)(ws + 262144);                // 8 KB
    unsigned short* zbf      = (unsigned short*)(ws + 270336);       // 16 MB
    int*            idxBest  = (int*)(ws + 270336 + 16777216);       // 512 KB
    float*          partials = (float*)(ws + 270336 + 16777216 + 524288);
    const size_t need = 270336 + 16777216 + 524288 + (size_t)nblocks * 2 * sizeof(float);

    if (ws_size >= need) {
        encode_prep_kernel<<<nblocks, THREADS, 0, stream>>>(
            x, W1, b1, W2, b2, W3, b3, W4, b4, E, zbf, Ebf, eNormH);
        scan_mfma_kernel<<<B_ROWS / 128, THREADS, 0, stream>>>(zbf, Ebf, eNormH,
                                                               idxBest);
        finish_rows_kernel<<<nblocks, THREADS, 0, stream>>>(
            x, W1, b1, W2, b2, W3, b3, W4, b4, W5, b5, W6, b6, W7, b7, W8, b8,
            E, idxBest, partials);
        finalize_kernel<<<1, 256, 0, stream>>>(partials, nblocks, (float*)d_out);
    } else {
        // fallback: proven fp32 monolithic path
        float* eNormFB = (float*)ws;                       // 8 KB
        float* partFB  = (float*)(ws + 16384);
        enorm_kernel<<<(NE + THREADS - 1) / THREADS, THREADS, 0, stream>>>(E, eNormFB);
        vqvae_main_kernel<<<nblocks, THREADS, 0, stream>>>(
            x, W1, b1, W2, b2, W3, b3, W4, b4, W5, b5, W6, b6, W7, b7, W8, b8,
            E, eNormFB, partFB);
        finalize_kernel<<<1, 256, 0, stream>>>(partFB, nblocks, (float*)d_out);
    }
}

// Round 6
// 99.357 us; speedup vs baseline: 27.3391x; 1.0143x over previous
//
#include <hip/hip_runtime.h>
#include <math.h>

#define B_ROWS 131072
#define NE 2048
#define ZDIM 64
#define THREADS 256

typedef __attribute__((ext_vector_type(8))) short short8;
typedef __attribute__((ext_vector_type(4))) float f32x4;

typedef const __attribute__((address_space(1))) void gv_t;
typedef __attribute__((address_space(3))) void lv_t;

// async global->LDS DMA, 16 B per lane. LDS dest = wave-uniform base + lane*16
// (m104); global src is per-lane (m173: pre-swizzled source pattern).
static __device__ __forceinline__ void gl_lds16(const void* g, void* l) {
    __builtin_amdgcn_global_load_lds((gv_t*)(uintptr_t)g,
                                     (lv_t*)(unsigned)(uintptr_t)l, 16, 0, 0);
}

// ---------------------------------------------------------------------------
// bf16 helpers (RNE), bit-exact with __float2bfloat16
// ---------------------------------------------------------------------------
static __device__ __forceinline__ unsigned short f2bf(float f) {
    unsigned int u = __float_as_uint(f);
    unsigned int r = (u + 0x7FFFu + ((u >> 16) & 1u)) >> 16;
    return (unsigned short)r;
}
static __device__ __forceinline__ float bf2f(unsigned short s) {
    return __uint_as_float(((unsigned int)s) << 16);
}

// ---------------------------------------------------------------------------
// Shared device helper: encoder (x -> z[64]), exact fp32.
// ---------------------------------------------------------------------------
__device__ __forceinline__ void encode_row(
    const float* __restrict__ xin,
    const float* __restrict__ W1, const float* __restrict__ b1,
    const float* __restrict__ W2, const float* __restrict__ b2,
    const float* __restrict__ W3, const float* __restrict__ b3,
    const float* __restrict__ W4, const float* __restrict__ b4,
    float* __restrict__ z) {
    float h1[16];
#pragma unroll
    for (int k = 0; k < 16; ++k) {
        float a = b1[k];
#pragma unroll
        for (int i = 0; i < 5; ++i) a = fmaf(xin[i], W1[i * 16 + k], a);
        h1[k] = fmaxf(a, 0.f);
    }
    float h2[32];
#pragma unroll
    for (int k = 0; k < 32; ++k) {
        float a = b2[k];
#pragma unroll
        for (int i = 0; i < 16; ++i) a = fmaf(h1[i], W2[i * 32 + k], a);
        h2[k] = fmaxf(a, 0.f);
    }
    float h3[16];
#pragma unroll
    for (int k = 0; k < 16; ++k) {
        float a = b3[k];
#pragma unroll
        for (int i = 0; i < 32; ++i) a = fmaf(h2[i], W3[i * 16 + k], a);
        h3[k] = fmaxf(a, 0.f);
    }
#pragma unroll
    for (int k = 0; k < ZDIM; ++k) {
        float a = b4[k];
#pragma unroll
        for (int i = 0; i < 16; ++i) a = fmaf(h3[i], W4[i * 64 + k], a);
        z[k] = a;
    }
}

// ---------------------------------------------------------------------------
// Kernel Z (fused): encoder -> zbf (bf16) for all rows; first 2048 global
// threads also prep the codebook: Ebf = bf16(E), eNormHalf = 0.5*|bf16(e)|^2.
// ---------------------------------------------------------------------------
__global__ __launch_bounds__(THREADS) void encode_prep_kernel(
    const float* __restrict__ x,
    const float* __restrict__ W1, const float* __restrict__ b1,
    const float* __restrict__ W2, const float* __restrict__ b2,
    const float* __restrict__ W3, const float* __restrict__ b3,
    const float* __restrict__ W4, const float* __restrict__ b4,
    const float* __restrict__ E,
    unsigned short* __restrict__ zbf,
    unsigned short* __restrict__ Ebf,
    float* __restrict__ eNormHalf) {
    const int row = blockIdx.x * THREADS + threadIdx.x;

    if (row < NE) {  // prep codebook (blocks 0..7 only)
        float s = 0.f;
#pragma unroll
        for (int d = 0; d < ZDIM; ++d) {
            unsigned short bb = f2bf(E[row * ZDIM + d]);
            Ebf[row * ZDIM + d] = bb;
            float v = bf2f(bb);
            s = fmaf(v, v, s);
        }
        eNormHalf[row] = 0.5f * s;
    }

    float xin[5];
#pragma unroll
    for (int i = 0; i < 5; ++i) xin[i] = x[row * 5 + i];
    float z[ZDIM];
    encode_row(xin, W1, b1, W2, b2, W3, b3, W4, b4, z);
#pragma unroll
    for (int q = 0; q < 8; ++q) {
        short8 v;
#pragma unroll
        for (int e = 0; e < 8; ++e) v[e] = (short)f2bf(z[q * 8 + e]);
        *(short8*)(zbf + row * ZDIM + q * 8) = v;
    }
}

// ---------------------------------------------------------------------------
// Kernel S: MFMA distance scan -> idxBest[row].
// R6 changes (inner loop only; DMA/barrier/reduce structure is R4/R5-proven):
//  (1) -eN folded into the MFMA C-operand (ci = {-eN}x4), deleting the 8
//      per-tile v_sub and the 8 zero-init movs.
//  (2) per-lane LDS read bases hoisted; per-tile reads are base + compile-time
//      immediate (t*2048 / t*64 / t*16) -> ds_read offset field, no addr VALU.
// ---------------------------------------------------------------------------
__global__ __launch_bounds__(THREADS, 2) void scan_mfma_kernel(
    const unsigned short* __restrict__ zbf,
    const unsigned short* __restrict__ Ebf,
    const float* __restrict__ eNormHalf,
    int* __restrict__ idxBest) {

    __shared__ unsigned short ebuf[2][128 * ZDIM];  // 2 x 16 KB
    __shared__ float enorm[NE];                     // 8 KB

    const int tid = threadIdx.x;
    const int lane = tid & 63;
    const int w = tid >> 6;
    const int l15 = lane & 15;
    const int lhi = lane >> 4;
    const int rowbase = blockIdx.x * 128 + w * 32;

    // ---- stage eNormHalf -> LDS (8 KB) ----
    {
        const float4* es = (const float4*)eNormHalf;
        float4* ed = (float4*)enorm;
        ed[tid] = es[tid];
        ed[tid + 256] = es[tid + 256];
    }

    // ---- A fragments: 2 m-tiles x 2 k-halves ----
    short8 afr[2][2];
#pragma unroll
    for (int mt = 0; mt < 2; ++mt)
#pragma unroll
        for (int h = 0; h < 2; ++h)
            afr[mt][h] = *(const short8*)(zbf + (rowbase + mt * 16 + l15) * ZDIM +
                                          h * 32 + lhi * 8);

    float best[2][4];
    int bidx[2][4];
#pragma unroll
    for (int mt = 0; mt < 2; ++mt)
#pragma unroll
        for (int r = 0; r < 4; ++r) {
            best[mt][r] = -INFINITY;
            bidx[mt][r] = 0;
        }

    // per-lane pre-swizzled global byte offset within a chunk-row group:
    // linear LDS slot sigma = q*256 + w*64 + lane -> (col = sigma>>3, kb' = sigma&7)
    // must receive global slot (col, kb' ^ (col&7)); col&7 == lane>>3.
    const int pi = (lane >> 3) * 128 + (((lane & 7) ^ (lane >> 3)) << 4);
    const char* gb = (const char*)Ebf;

    // per-lane LDS read bases (R3-validated swizzle), hoisted out of the loop
    const char* base0 =
        (const char*)&ebuf[0][0] + l15 * 128 + ((lhi ^ (l15 & 7)) << 4);
    const char* base1 =
        (const char*)&ebuf[0][0] + l15 * 128 + (((4 + lhi) ^ (l15 & 7)) << 4);
    const float* enb = enorm + l15;

    // ---- prologue: issue DMA for chunks 0 and 1 ----
#pragma unroll
    for (int q = 0; q < 4; ++q)
        gl_lds16(gb + 0 * 16384 + q * 4096 + w * 1024 + pi,
                 (char*)&ebuf[0][0] + q * 4096 + w * 1024);
#pragma unroll
    for (int q = 0; q < 4; ++q)
        gl_lds16(gb + 1 * 16384 + q * 4096 + w * 1024 + pi,
                 (char*)&ebuf[1][0] + q * 4096 + w * 1024);

    // full drain once (also publishes the enorm ds_writes)
    __syncthreads();

    for (int c = 0; c < 16; ++c) {
        const int cur = c & 1;
        // chunk c ready when only the newest 4 DMAs (chunk c+1) are in flight
        if (c < 15)
            asm volatile("s_waitcnt vmcnt(4)" ::: "memory");
        else
            asm volatile("s_waitcnt vmcnt(0)" ::: "memory");
        asm volatile("s_barrier" ::: "memory");

        const char* eb0 = base0 + cur * 16384;
        const char* eb1 = base1 + cur * 16384;
        const float* enc = enb + c * 128;
        const int nb = c * 128 + l15;

#pragma unroll
        for (int t = 0; t < 8; ++t) {
            short8 b0 = *(const short8*)(eb0 + t * 2048);
            short8 b1 = *(const short8*)(eb1 + t * 2048);
            const float negE = -enc[t * 16];
            f32x4 ci;
            ci[0] = negE; ci[1] = negE; ci[2] = negE; ci[3] = negE;
            f32x4 acc0 = __builtin_amdgcn_mfma_f32_16x16x32_bf16(afr[0][0], b0, ci, 0, 0, 0);
            acc0 = __builtin_amdgcn_mfma_f32_16x16x32_bf16(afr[0][1], b1, acc0, 0, 0, 0);
            f32x4 acc1 = __builtin_amdgcn_mfma_f32_16x16x32_bf16(afr[1][0], b0, ci, 0, 0, 0);
            acc1 = __builtin_amdgcn_mfma_f32_16x16x32_bf16(afr[1][1], b1, acc1, 0, 0, 0);

            const int n = nb + t * 16;
#pragma unroll
            for (int mt = 0; mt < 2; ++mt) {
                f32x4 A = mt ? acc1 : acc0;
#pragma unroll
                for (int r = 0; r < 4; ++r) {
                    float s = A[r];
                    if (s > best[mt][r]) {  // strict '>' keeps first index
                        best[mt][r] = s;
                        bidx[mt][r] = n;
                    }
                }
            }
        }
        // all waves done reading ebuf[cur] before DMA overwrites it
        asm volatile("s_barrier" ::: "memory");
        if (c + 2 < 16) {
#pragma unroll
            for (int q = 0; q < 4; ++q)
                gl_lds16(gb + (c + 2) * 16384 + q * 4096 + w * 1024 + pi,
                         (char*)&ebuf[cur][0] + q * 4096 + w * 1024);
        }
    }

    // ---- cross-lane reduction (16 lanes per row-group) + write ----
#pragma unroll
    for (int mt = 0; mt < 2; ++mt)
#pragma unroll
        for (int r = 0; r < 4; ++r) {
            float s = best[mt][r];
            int ix = bidx[mt][r];
#pragma unroll
            for (int off = 1; off < 16; off <<= 1) {
                float os = __shfl_xor(s, off);
                int oi = __shfl_xor(ix, off);
                bool take = (os > s) || (os == s && oi < ix);
                s = take ? os : s;
                ix = take ? oi : ix;
            }
            if (l15 == 0)
                idxBest[rowbase + mt * 16 + lhi * 4 + r] = ix;
        }
}

// ---------------------------------------------------------------------------
// Kernel F: gather z_q (fp32 E), recompute z (fp32), decoder, losses.
// ---------------------------------------------------------------------------
__global__ __launch_bounds__(THREADS) void finish_rows_kernel(
    const float* __restrict__ x,
    const float* __restrict__ W1, const float* __restrict__ b1,
    const float* __restrict__ W2, const float* __restrict__ b2,
    const float* __restrict__ W3, const float* __restrict__ b3,
    const float* __restrict__ W4, const float* __restrict__ b4,
    const float* __restrict__ W5, const float* __restrict__ b5,
    const float* __restrict__ W6, const float* __restrict__ b6,
    const float* __restrict__ W7, const float* __restrict__ b7,
    const float* __restrict__ W8, const float* __restrict__ b8,
    const float* __restrict__ E, const int* __restrict__ idxBest,
    float* __restrict__ partials) {

    const int row = blockIdx.x * THREADS + threadIdx.x;
    const int bidx = idxBest[row];

    float xin[5];
#pragma unroll
    for (int i = 0; i < 5; ++i) xin[i] = x[row * 5 + i];
    float z[ZDIM];
    encode_row(xin, W1, b1, W2, b2, W3, b3, W4, b4, z);

    float zq[ZDIM];
#pragma unroll
    for (int d = 0; d < ZDIM; ++d) zq[d] = E[bidx * ZDIM + d];

    float emb = 0.f;
#pragma unroll
    for (int d = 0; d < ZDIM; ++d) {
        float diff = z[d] - zq[d];
        emb = fmaf(diff, diff, emb);
    }
    emb *= 2.0f;  // embed + BETA*commit, BETA=1

    float g1[16];
#pragma unroll
    for (int k = 0; k < 16; ++k) {
        float a = b5[k];
#pragma unroll
        for (int i = 0; i < ZDIM; ++i) a = fmaf(zq[i], W5[i * 16 + k], a);
        g1[k] = fmaxf(a, 0.f);
    }
    float g2[32];
#pragma unroll
    for (int k = 0; k < 32; ++k) {
        float a = b6[k];
#pragma unroll
        for (int i = 0; i < 16; ++i) a = fmaf(g1[i], W6[i * 32 + k], a);
        g2[k] = fmaxf(a, 0.f);
    }
    float g3[16];
#pragma unroll
    for (int k = 0; k < 16; ++k) {
        float a = b7[k];
#pragma unroll
        for (int i = 0; i < 32; ++i) a = fmaf(g2[i], W7[i * 16 + k], a);
        g3[k] = fmaxf(a, 0.f);
    }
    float l2 = 0.f;
#pragma unroll
    for (int k = 0; k < 5; ++k) {
        float a = b8[k];
#pragma unroll
        for (int i = 0; i < 16; ++i) a = fmaf(g3[i], W8[i * 5 + k], a);
        float diff = xin[k] - a;
        l2 = fmaf(diff, diff, l2);
    }

#pragma unroll
    for (int off = 32; off > 0; off >>= 1) {
        l2 += __shfl_down(l2, off);
        emb += __shfl_down(emb, off);
    }
    __shared__ float sl[THREADS / 64], se[THREADS / 64];
    const int wid = threadIdx.x >> 6;
    if ((threadIdx.x & 63) == 0) {
        sl[wid] = l2;
        se[wid] = emb;
    }
    __syncthreads();
    if (threadIdx.x == 0) {
        float L = 0.f, Em = 0.f;
#pragma unroll
        for (int ww = 0; ww < THREADS / 64; ++ww) {
            L += sl[ww];
            Em += se[ww];
        }
        partials[2 * blockIdx.x + 0] = L;
        partials[2 * blockIdx.x + 1] = Em;
    }
}

// ---------------------------------------------------------------------------
// Fallback path kernels (ws too small) — proven R1 monolithic fp32.
// ---------------------------------------------------------------------------
__global__ void enorm_kernel(const float* __restrict__ E,
                             float* __restrict__ eNormHalf) {
    int j = blockIdx.x * blockDim.x + threadIdx.x;
    if (j < NE) {
        float s = 0.f;
#pragma unroll
        for (int d = 0; d < ZDIM; ++d) {
            float v = E[j * ZDIM + d];
            s = fmaf(v, v, s);
        }
        eNormHalf[j] = 0.5f * s;
    }
}

__global__ __launch_bounds__(THREADS) void vqvae_main_kernel(
    const float* __restrict__ x,
    const float* __restrict__ W1, const float* __restrict__ b1,
    const float* __restrict__ W2, const float* __restrict__ b2,
    const float* __restrict__ W3, const float* __restrict__ b3,
    const float* __restrict__ W4, const float* __restrict__ b4,
    const float* __restrict__ W5, const float* __restrict__ b5,
    const float* __restrict__ W6, const float* __restrict__ b6,
    const float* __restrict__ W7, const float* __restrict__ b7,
    const float* __restrict__ W8, const float* __restrict__ b8,
    const float* __restrict__ E, const float* __restrict__ eNormHalf,
    float* __restrict__ partials) {

    const int row = blockIdx.x * blockDim.x + threadIdx.x;
    float l2 = 0.f, emb = 0.f;

    if (row < B_ROWS) {
        float xin[5];
#pragma unroll
        for (int i = 0; i < 5; ++i) xin[i] = x[row * 5 + i];
        float z[ZDIM];
        encode_row(xin, W1, b1, W2, b2, W3, b3, W4, b4, z);

        float best = -INFINITY;
        int bidx = 0;
        const float4* __restrict__ E4 = reinterpret_cast<const float4*>(E);
        for (int j = 0; j < NE; ++j) {
            float a0 = 0.f, a1 = 0.f, a2 = 0.f, a3 = 0.f;
#pragma unroll
            for (int q = 0; q < ZDIM / 4; ++q) {
                float4 e = E4[j * (ZDIM / 4) + q];
                a0 = fmaf(z[4 * q + 0], e.x, a0);
                a1 = fmaf(z[4 * q + 1], e.y, a1);
                a2 = fmaf(z[4 * q + 2], e.z, a2);
                a3 = fmaf(z[4 * q + 3], e.w, a3);
            }
            float score = ((a0 + a1) + (a2 + a3)) - eNormHalf[j];
            if (score > best) { best = score; bidx = j; }
        }
        float zq[ZDIM];
#pragma unroll
        for (int d = 0; d < ZDIM; ++d) zq[d] = E[bidx * ZDIM + d];
#pragma unroll
        for (int d = 0; d < ZDIM; ++d) {
            float diff = z[d] - zq[d];
            emb = fmaf(diff, diff, emb);
        }
        emb *= 2.0f;
        float g1[16];
#pragma unroll
        for (int k = 0; k < 16; ++k) {
            float a = b5[k];
#pragma unroll
            for (int i = 0; i < ZDIM; ++i) a = fmaf(zq[i], W5[i * 16 + k], a);
            g1[k] = fmaxf(a, 0.f);
        }
        float g2[32];
#pragma unroll
        for (int k = 0; k < 32; ++k) {
            float a = b6[k];
#pragma unroll
            for (int i = 0; i < 16; ++i) a = fmaf(g1[i], W6[i * 32 + k], a);
            g2[k] = fmaxf(a, 0.f);
        }
        float g3[16];
#pragma unroll
        for (int k = 0; k < 16; ++k) {
            float a = b7[k];
#pragma unroll
            for (int i = 0; i < 32; ++i) a = fmaf(g2[i], W7[i * 16 + k], a);
            g3[k] = fmaxf(a, 0.f);
        }
#pragma unroll
        for (int k = 0; k < 5; ++k) {
            float a = b8[k];
#pragma unroll
            for (int i = 0; i < 16; ++i) a = fmaf(g3[i], W8[i * 5 + k], a);
            float diff = xin[k] - a;
            l2 = fmaf(diff, diff, l2);
        }
    }
#pragma unroll
    for (int off = 32; off > 0; off >>= 1) {
        l2 += __shfl_down(l2, off);
        emb += __shfl_down(emb, off);
    }
    __shared__ float sl[THREADS / 64], se[THREADS / 64];
    const int wid = threadIdx.x >> 6;
    if ((threadIdx.x & 63) == 0) { sl[wid] = l2; se[wid] = emb; }
    __syncthreads();
    if (threadIdx.x == 0) {
        float L = 0.f, Em = 0.f;
#pragma unroll
        for (int ww = 0; ww < THREADS / 64; ++ww) { L += sl[ww]; Em += se[ww]; }
        partials[2 * blockIdx.x + 0] = L;
        partials[2 * blockIdx.x + 1] = Em;
    }
}

// ---------------------------------------------------------------------------
// Final reduce: per-block partials (double accumulation) -> 3 scalars.
// ---------------------------------------------------------------------------
__global__ void finalize_kernel(const float* __restrict__ partials, int nblocks,
                                float* __restrict__ out) {
    __shared__ double sl[256], se[256];
    double a = 0.0, b = 0.0;
    for (int i = threadIdx.x; i < nblocks; i += 256) {
        a += (double)partials[2 * i + 0];
        b += (double)partials[2 * i + 1];
    }
    sl[threadIdx.x] = a;
    se[threadIdx.x] = b;
    __syncthreads();
    for (int s = 128; s > 0; s >>= 1) {
        if (threadIdx.x < s) {
            sl[threadIdx.x] += sl[threadIdx.x + s];
            se[threadIdx.x] += se[threadIdx.x + s];
        }
        __syncthreads();
    }
    if (threadIdx.x == 0) {
        double sum_l2 = sl[0];
        double embd = se[0];
        double c = -0.5 * 5.0 * log(2.0 * M_PI / 10.0);
        double neg_pxz = -(c - 5.0 * sum_l2);
        out[0] = (float)(neg_pxz + embd);
        out[1] = (float)neg_pxz;
        out[2] = (float)embd;
    }
}

// ---------------------------------------------------------------------------
extern "C" void kernel_launch(void* const* d_in, const int* in_sizes, int n_in,
                              void* d_out, int out_size, void* d_ws,
                              size_t ws_size, hipStream_t stream) {
    const float* x = (const float*)d_in[0];
    const float* W1 = (const float*)d_in[1];
    const float* b1 = (const float*)d_in[2];
    const float* W2 = (const float*)d_in[3];
    const float* b2 = (const float*)d_in[4];
    const float* W3 = (const float*)d_in[5];
    const float* b3 = (const float*)d_in[6];
    const float* W4 = (const float*)d_in[7];
    const float* b4 = (const float*)d_in[8];
    const float* W5 = (const float*)d_in[9];
    const float* b5 = (const float*)d_in[10];
    const float* W6 = (const float*)d_in[11];
    const float* b6 = (const float*)d_in[12];
    const float* W7 = (const float*)d_in[13];
    const float* b7 = (const float*)d_in[14];
    const float* W8 = (const float*)d_in[15];
    const float* b8 = (const float*)d_in[16];
    const float* E = (const float*)d_in[17];

    const int nblocks = B_ROWS / THREADS;  // 512

    // ws layout (16B-aligned segments)
    char* ws = (char*)d_ws;
    unsigned short* Ebf      = (unsigned short*)(ws + 0);            // 256 KB
    float*          eNormH   = (float*)(ws + 262144);                // 8 KB
    unsigned short* zbf      = (unsigned short*)(ws + 270336);       // 16 MB
    int*            idxBest  = (int*)(ws + 270336 + 16777216);       // 512 KB
    float*          partials = (float*)(ws + 270336 + 16777216 + 524288);
    const size_t need = 270336 + 16777216 + 524288 + (size_t)nblocks * 2 * sizeof(float);

    if (ws_size >= need) {
        encode_prep_kernel<<<nblocks, THREADS, 0, stream>>>(
            x, W1, b1, W2, b2, W3, b3, W4, b4, E, zbf, Ebf, eNormH);
        scan_mfma_kernel<<<B_ROWS / 128, THREADS, 0, stream>>>(zbf, Ebf, eNormH,
                                                               idxBest);
        finish_rows_kernel<<<nblocks, THREADS, 0, stream>>>(
            x, W1, b1, W2, b2, W3, b3, W4, b4, W5, b5, W6, b6, W7, b7, W8, b8,
            E, idxBest, partials);
        finalize_kernel<<<1, 256, 0, stream>>>(partials, nblocks, (float*)d_out);
    } else {
        // fallback: proven fp32 monolithic path
        float* eNormFB = (float*)ws;                       // 8 KB
        float* partFB  = (float*)(ws + 16384);
        enorm_kernel<<<(NE + THREADS - 1) / THREADS, THREADS, 0, stream>>>(E, eNormFB);
        vqvae_main_kernel<<<nblocks, THREADS, 0, stream>>>(
            x, W1, b1, W2, b2, W3, b3, W4, b4, W5, b5, W6, b6, W7, b7, W8, b8,
            E, eNormFB, partFB);
        finalize_kernel<<<1, 256, 0, stream>>>(partFB, nblocks, (float*)d_out);
    }
}